// Round 9
// baseline (887.489 us; speedup 1.0000x reference)
//
#include <hip/hip_runtime.h>
#include <math.h>

#define T_TOK 32768
#define DIM   2048
#define E_N   64
#define KP    2048   // padded reduction length (row 0 of Wt is zero)

// ws layout (floats): [0, 131072) Wt[2048][64]; [131072, +32768*64) logitsT[64][T]
#define WS_WT_FLOATS (KP * E_N)

typedef float v4f __attribute__((ext_vector_type(4)));

// ---------------- kernel 0: shift/pad + transpose weight -> Wt[k][e] ----------------
__global__ __launch_bounds__(256) void k_padw(const float* __restrict__ w,
                                              float* __restrict__ wt) {
  int idx = blockIdx.x * 256 + threadIdx.x;   // 0 .. 2048*64-1
  int k = idx >> 6;
  int e = idx & 63;
  wt[idx] = (k == 0) ? 0.f : w[e * 2047 + (k - 1)];
}

// ---------------- kernel 1: logitsT = (x[:,1:] @ W^T)^T ----------------
// Row-per-lane, weights-in-SGPR, 2 rows/lane (scalar traffic amortized over
// 128 FMAs per W chunk), 16 waves/block (k-split 16: wave owns 128 k) so each
// CU runs 4 waves/SIMD to cover the s_load drain latency. Grid 256 = 1
// block/CU. Reduce: 4 sequential stages into 4 LDS slots, two row-phases
// through one 64 KB buffer. Per-accumulator k-order identical to R8.
__global__ __launch_bounds__(1024, 4) void k_logits(const float* __restrict__ x,
                                                    const float* __restrict__ wt,
                                                    float* __restrict__ logitsT) {
  __shared__ float buf[4][E_N][64];   // 64 KB
  const int tid  = threadIdx.x;
  const int lane = tid & 63;
  const int wv   = __builtin_amdgcn_readfirstlane(tid >> 6);  // 0..15 (SGPR)
  const int kbase = wv * 128;
  const int rowA = blockIdx.x * 128 + lane;   // rows 0..63 of block
  // rowB = rowA + 64                          // rows 64..127 of block

  const float* xpA = x + (size_t)rowA * DIM + kbase;          // per-lane
  const float* xpB = xpA + (size_t)64 * DIM;
  const float* wkbase = wt + (size_t)kbase * E_N;             // wave-uniform (SGPR)

  float accA[E_N], accB[E_N];
#pragma unroll
  for (int e = 0; e < E_N; ++e) { accA[e] = 0.f; accB[e] = 0.f; }

  for (int g = 0; g < 8; ++g) {        // 8 groups x 16 k = 128 k per wave
    v4f xa[4], xb[4];
#pragma unroll
    for (int q = 0; q < 4; ++q) {
      xa[q] = *(const v4f*)(xpA + q * 4);
      xb[q] = *(const v4f*)(xpB + q * 4);
    }
    const float* wk = wkbase + g * 16 * E_N;   // uniform
#pragma unroll
    for (int q = 0; q < 4; ++q) {
#pragma unroll
      for (int kk = 0; kk < 4; ++kk) {
        const float xkA = xa[q][kk];
        const float xkB = xb[q][kk];
        const float* wrow = wk + (q * 4 + kk) * E_N;   // uniform -> s_load
#pragma unroll
        for (int e = 0; e < E_N; ++e) {
          const float we = wrow[e];
          accA[e] = fmaf(xkA, we, accA[e]);
          accB[e] = fmaf(xkB, we, accB[e]);
        }
      }
    }
    xpA += 16; xpB += 16;
  }

  // ---- reduce phase A: rows blk*128 + 0..63 ----
  if (wv < 4) {
#pragma unroll
    for (int e = 0; e < E_N; ++e) buf[wv][e][lane] = accA[e];
  }
  __syncthreads();
  if (wv >= 4 && wv < 8) {
#pragma unroll
    for (int e = 0; e < E_N; ++e) buf[wv - 4][e][lane] += accA[e];
  }
  __syncthreads();
  if (wv >= 8 && wv < 12) {
#pragma unroll
    for (int e = 0; e < E_N; ++e) buf[wv - 8][e][lane] += accA[e];
  }
  __syncthreads();
  if (wv >= 12) {
#pragma unroll
    for (int e = 0; e < E_N; ++e) buf[wv - 12][e][lane] += accA[e];
  }
  __syncthreads();
  {
    const int r  = tid & 63;
    const int e0 = (tid >> 6) * 4;     // 16 groups x 4 experts
#pragma unroll
    for (int i = 0; i < 4; ++i) {
      const int e = e0 + i;
      const float v = ((buf[0][e][r] + buf[1][e][r]) + buf[2][e][r]) + buf[3][e][r];
      logitsT[(size_t)e * T_TOK + blockIdx.x * 128 + r] = v;
    }
  }
  __syncthreads();   // buf reuse

  // ---- reduce phase B: rows blk*128 + 64..127 ----
  if (wv < 4) {
#pragma unroll
    for (int e = 0; e < E_N; ++e) buf[wv][e][lane] = accB[e];
  }
  __syncthreads();
  if (wv >= 4 && wv < 8) {
#pragma unroll
    for (int e = 0; e < E_N; ++e) buf[wv - 4][e][lane] += accB[e];
  }
  __syncthreads();
  if (wv >= 8 && wv < 12) {
#pragma unroll
    for (int e = 0; e < E_N; ++e) buf[wv - 8][e][lane] += accB[e];
  }
  __syncthreads();
  if (wv >= 12) {
#pragma unroll
    for (int e = 0; e < E_N; ++e) buf[wv - 12][e][lane] += accB[e];
  }
  __syncthreads();
  {
    const int r  = tid & 63;
    const int e0 = (tid >> 6) * 4;
#pragma unroll
    for (int i = 0; i < 4; ++i) {
      const int e = e0 + i;
      const float v = ((buf[0][e][r] + buf[1][e][r]) + buf[2][e][r]) + buf[3][e][r];
      logitsT[(size_t)e * T_TOK + blockIdx.x * 128 + 64 + r] = v;
    }
  }
}

// ---------------- kernel 2: per-row group-limited top-k routing ----------------
__global__ __launch_bounds__(256) void k_route(const float* __restrict__ logitsT,
                                               const float* __restrict__ bias,
                                               float* __restrict__ out_w,
                                               float* __restrict__ out_i) {
  __shared__ float bl[E_N];
  if (threadIdx.x < E_N) bl[threadIdx.x] = bias[threadIdx.x];
  __syncthreads();

  const int row = blockIdx.x * 256 + threadIdx.x;      // grid sized exactly
  const float* lp = logitsT + row;                     // column access: lane-coalesced

  float sb[E_N];                                       // sigmoid(logit) + bias
#pragma unroll
  for (int e = 0; e < E_N; ++e)
    sb[e] = 1.f / (1.f + expf(-lp[(size_t)e * T_TOK])) + bl[e];

  // group scores: sum of top-2 per group of 8
  float gs[8];
#pragma unroll
  for (int g = 0; g < 8; ++g) {
    float m1 = -__builtin_inff(), m2 = -__builtin_inff();
#pragma unroll
    for (int j = 0; j < 8; ++j) {
      float v = sb[g * 8 + j];
      if (v > m1) { m2 = m1; m1 = v; }
      else if (v > m2) { m2 = v; }
    }
    gs[g] = m1 + m2;
  }

  // top-4 groups (strict > : lower index wins ties, matches lax.top_k)
  unsigned gmask = 0;
#pragma unroll
  for (int tsel = 0; tsel < 4; ++tsel) {
    float best = -__builtin_inff(); int bi = 0;
#pragma unroll
    for (int g = 0; g < 8; ++g) {
      bool avail = ((gmask >> g) & 1u) == 0u;
      if (avail && gs[g] > best) { best = gs[g]; bi = g; }
    }
    gmask |= (1u << bi);
  }

  // taken-mask: pre-ban experts in dropped groups
  unsigned long long tm = 0ull;
#pragma unroll
  for (int g = 0; g < 8; ++g)
    if (((gmask >> g) & 1u) == 0u) tm |= (0xFFull << (8 * g));

  // top-8 experts over allowed groups
  float wv[8]; int io[8]; float wsum = 0.f;
#pragma unroll
  for (int tsel = 0; tsel < 8; ++tsel) {
    float best = -__builtin_inff(); int bi = 0;
#pragma unroll
    for (int e = 0; e < E_N; ++e) {
      bool avail = ((tm >> e) & 1ull) == 0ull;
      if (avail && sb[e] > best) { best = sb[e]; bi = e; }
    }
    tm |= (1ull << bi);
    float sv = best - bl[bi];        // original sigmoid score (bias removed)
    wv[tsel] = sv; io[tsel] = bi; wsum += sv;
  }

  const float scale = 2.5f / wsum;
  float4 w0 = make_float4(wv[0] * scale, wv[1] * scale, wv[2] * scale, wv[3] * scale);
  float4 w1 = make_float4(wv[4] * scale, wv[5] * scale, wv[6] * scale, wv[7] * scale);
  float4 i0 = make_float4((float)io[0], (float)io[1], (float)io[2], (float)io[3]);
  float4 i1 = make_float4((float)io[4], (float)io[5], (float)io[6], (float)io[7]);
  *(float4*)(out_w + (size_t)row * 8)     = w0;
  *(float4*)(out_w + (size_t)row * 8 + 4) = w1;
  *(float4*)(out_i + (size_t)row * 8)     = i0;
  *(float4*)(out_i + (size_t)row * 8 + 4) = i1;
}

extern "C" void kernel_launch(void* const* d_in, const int* in_sizes, int n_in,
                              void* d_out, int out_size, void* d_ws, size_t ws_size,
                              hipStream_t stream) {
  const float* x    = (const float*)d_in[0];
  const float* wgt  = (const float*)d_in[1];
  const float* bias = (const float*)d_in[2];
  float* out     = (float*)d_out;
  float* wtbuf   = (float*)d_ws;
  float* logitsT = (float*)d_ws + WS_WT_FLOATS;

  k_padw  <<<(KP * E_N) / 256, 256, 0, stream>>>(wgt, wtbuf);
  k_logits<<<T_TOK / 128,      1024, 0, stream>>>(x, wtbuf, logitsT);
  k_route <<<T_TOK / 256,      256, 0, stream>>>(logitsT, bias,
                                                 out, out + (size_t)T_TOK * 8);
}

// Round 10
// 242.550 us; speedup vs baseline: 3.6590x; 3.6590x over previous
//
#include <hip/hip_runtime.h>
#include <math.h>

#define T_TOK 32768
#define DIM   2048
#define E_N   64
#define KP    2048   // padded K (k==0 column is zero)

typedef float v4f    __attribute__((ext_vector_type(4)));
typedef float f32x4  __attribute__((ext_vector_type(4)));
typedef short bf16x8 __attribute__((ext_vector_type(8)));
typedef unsigned int u32x4 __attribute__((ext_vector_type(4)));

#define WB_USHORTS (3 * E_N * KP)        // 3 bf16 splits of W^T: 786432 B
#define WS_LOGITS_OFF (WB_USHORTS / 2)   // float offset of logitsT in ws
#define SOFF (E_N * KP)                  // split stride (ushorts)
#define TOFF (16 * KP)                   // expert-tile stride (ushorts)

__device__ __forceinline__ unsigned short rne16(unsigned u) {
  return (unsigned short)((u + 0x7fffu + ((u >> 16) & 1u)) >> 16);
}
__device__ __forceinline__ float bits2f(unsigned u) {
  union { unsigned u; float f; } c; c.u = u; return c.f;
}
__device__ __forceinline__ unsigned f2bits(float f) {
  union { float f; unsigned u; } c; c.f = f; return c.u;
}
__device__ __forceinline__ unsigned cvtpk(float a, float b) {  // lo=bf16(a), hi=bf16(b), RNE
  unsigned r;
  asm("v_cvt_pk_bf16_f32 %0, %1, %2" : "=v"(r) : "v"(a), "v"(b));
  return r;
}
__device__ __forceinline__ bf16x8 ldw(const unsigned short* p) {
  union { u32x4 u; bf16x8 b; } c; c.u = *(const u32x4*)p; return c.b;
}
__device__ __forceinline__ bf16x8 pack4(unsigned a, unsigned b, unsigned c, unsigned d) {
  union { u32x4 u; bf16x8 b; } t; t.u.x = a; t.u.y = b; t.u.z = c; t.u.w = d; return t.b;
}

// ---------------- kernel 0: W -> 3 bf16 splits, transposed+padded: wb[s][e][k] ----------------
__global__ __launch_bounds__(256) void k_prep(const float* __restrict__ w,
                                              unsigned short* __restrict__ wb) {
  int idx = blockIdx.x * 256 + threadIdx.x;    // e*2048 + k
  int e = idx >> 11, k = idx & 2047;
  float f = (k == 0) ? 0.f : w[e * 2047 + (k - 1)];
  unsigned short b0 = rne16(f2bits(f));
  float r1 = f - bits2f((unsigned)b0 << 16);   // exact (Sterbenz)
  unsigned short b1 = rne16(f2bits(r1));
  float r2 = r1 - bits2f((unsigned)b1 << 16);  // exact
  unsigned short b2 = rne16(f2bits(r2));
  wb[idx] = b0;
  wb[idx + SOFF] = b1;
  wb[idx + 2 * SOFF] = b2;
}

// ---------------- kernel 1: logitsT[e][tok] via 6-pass bf16-split MFMA ----------------
// wave = 16 tokens x 64 experts x full K. A-operand = W (M=experts), B = x
// (N=tokens) -> D rows=experts, cols=tokens -> coalesced logitsT stores.
// Lane: l15 = lane&15 (token / expert-row in frags), kq = (lane>>4)*8.
__global__ __launch_bounds__(256, 2) void k_logits(const float* __restrict__ x,
                                                   const unsigned short* __restrict__ wb,
                                                   float* __restrict__ logitsT) {
  const int tid  = threadIdx.x;
  const int lane = tid & 63;
  const int l15  = lane & 15;
  const int kq   = (lane >> 4) * 8;
  const int tok0 = (blockIdx.x * 4 + (tid >> 6)) * 16;

  const float* xr = x + (size_t)(tok0 + l15) * DIM + kq;      // per-lane 32B slices
  const unsigned short* wp = wb + (size_t)l15 * KP + kq;      // + s*SOFF + t*TOFF + kc*32

  f32x4 acc[4];
#pragma unroll
  for (int t = 0; t < 4; ++t) acc[t] = (f32x4)(0.f);

  // two-slot x pipeline: slot A holds kc, slot B holds kc+1
  v4f pa0 = *(const v4f*)(xr);
  v4f pa1 = *(const v4f*)(xr + 4);
  v4f pb0 = *(const v4f*)(xr + 32);
  v4f pb1 = *(const v4f*)(xr + 36);

  auto body = [&](v4f& c0, v4f& c1, int kc) {
    // W frags for this k-chunk (L2/L1-resident)
    bf16x8 wf[3][4];
    const unsigned short* wk = wp + kc * 32;
#pragma unroll
    for (int s = 0; s < 3; ++s)
#pragma unroll
      for (int t = 0; t < 4; ++t)
        wf[s][t] = ldw(wk + s * SOFF + t * TOFF);
    // prefetch x for kc+2 (guarded, wave-uniform branch condition)
    const float* nx = xr + ((kc + 2 < 64) ? (kc + 2) * 32 : 0);
    v4f n0 = *(const v4f*)(nx);
    v4f n1 = *(const v4f*)(nx + 4);
    // 3-way bf16 split of the 8 x values (residuals exact by Sterbenz)
    unsigned c00 = cvtpk(c0.x, c0.y), c01 = cvtpk(c0.z, c0.w);
    unsigned c02 = cvtpk(c1.x, c1.y), c03 = cvtpk(c1.z, c1.w);
    float r0 = c0.x - bits2f(c00 << 16), r1 = c0.y - bits2f(c00 & 0xFFFF0000u);
    float r2 = c0.z - bits2f(c01 << 16), r3 = c0.w - bits2f(c01 & 0xFFFF0000u);
    float r4 = c1.x - bits2f(c02 << 16), r5 = c1.y - bits2f(c02 & 0xFFFF0000u);
    float r6 = c1.z - bits2f(c03 << 16), r7 = c1.w - bits2f(c03 & 0xFFFF0000u);
    unsigned d0 = cvtpk(r0, r1), d1 = cvtpk(r2, r3);
    unsigned d2 = cvtpk(r4, r5), d3 = cvtpk(r6, r7);
    float s0 = r0 - bits2f(d0 << 16), s1 = r1 - bits2f(d0 & 0xFFFF0000u);
    float s2 = r2 - bits2f(d1 << 16), s3 = r3 - bits2f(d1 & 0xFFFF0000u);
    float s4 = r4 - bits2f(d2 << 16), s5 = r5 - bits2f(d2 & 0xFFFF0000u);
    float s6 = r6 - bits2f(d3 << 16), s7 = r7 - bits2f(d3 & 0xFFFF0000u);
    unsigned e0 = cvtpk(s0, s1), e1 = cvtpk(s2, s3);
    unsigned e2 = cvtpk(s4, s5), e3 = cvtpk(s6, s7);
    bf16x8 x0 = pack4(c00, c01, c02, c03);
    bf16x8 x1 = pack4(d0, d1, d2, d3);
    bf16x8 x2 = pack4(e0, e1, e2, e3);
    // 6 passes, smallest-magnitude first; all accumulate into the same acc
#pragma unroll
    for (int t = 0; t < 4; ++t)
      acc[t] = __builtin_amdgcn_mfma_f32_16x16x32_bf16(wf[2][t], x0, acc[t], 0, 0, 0);
#pragma unroll
    for (int t = 0; t < 4; ++t)
      acc[t] = __builtin_amdgcn_mfma_f32_16x16x32_bf16(wf[1][t], x1, acc[t], 0, 0, 0);
#pragma unroll
    for (int t = 0; t < 4; ++t)
      acc[t] = __builtin_amdgcn_mfma_f32_16x16x32_bf16(wf[0][t], x2, acc[t], 0, 0, 0);
#pragma unroll
    for (int t = 0; t < 4; ++t)
      acc[t] = __builtin_amdgcn_mfma_f32_16x16x32_bf16(wf[1][t], x0, acc[t], 0, 0, 0);
#pragma unroll
    for (int t = 0; t < 4; ++t)
      acc[t] = __builtin_amdgcn_mfma_f32_16x16x32_bf16(wf[0][t], x1, acc[t], 0, 0, 0);
#pragma unroll
    for (int t = 0; t < 4; ++t)
      acc[t] = __builtin_amdgcn_mfma_f32_16x16x32_bf16(wf[0][t], x0, acc[t], 0, 0, 0);
    c0 = n0; c1 = n1;
  };

  for (int kc = 0; kc < 64; kc += 2) {
    body(pa0, pa1, kc);
    body(pb0, pb1, kc + 1);
  }

  // D: expert = t*16 + (lane>>4)*4 + r, token = tok0 + l15 -> coalesced
#pragma unroll
  for (int t = 0; t < 4; ++t)
#pragma unroll
    for (int r = 0; r < 4; ++r) {
      const int e = t * 16 + (lane >> 4) * 4 + r;
      logitsT[(size_t)e * T_TOK + tok0 + l15] = acc[t][r];
    }
}

// ---------------- kernel 2: per-row group-limited top-k routing ----------------
__global__ __launch_bounds__(256) void k_route(const float* __restrict__ logitsT,
                                               const float* __restrict__ bias,
                                               float* __restrict__ out_w,
                                               float* __restrict__ out_i) {
  __shared__ float bl[E_N];
  if (threadIdx.x < E_N) bl[threadIdx.x] = bias[threadIdx.x];
  __syncthreads();

  const int row = blockIdx.x * 256 + threadIdx.x;
  const float* lp = logitsT + row;                     // column access: coalesced

  float sb[E_N];
#pragma unroll
  for (int e = 0; e < E_N; ++e)
    sb[e] = 1.f / (1.f + expf(-lp[(size_t)e * T_TOK])) + bl[e];

  float gs[8];
#pragma unroll
  for (int g = 0; g < 8; ++g) {
    float m1 = -__builtin_inff(), m2 = -__builtin_inff();
#pragma unroll
    for (int j = 0; j < 8; ++j) {
      float v = sb[g * 8 + j];
      if (v > m1) { m2 = m1; m1 = v; }
      else if (v > m2) { m2 = v; }
    }
    gs[g] = m1 + m2;
  }

  unsigned gmask = 0;
#pragma unroll
  for (int tsel = 0; tsel < 4; ++tsel) {
    float best = -__builtin_inff(); int bi = 0;
#pragma unroll
    for (int g = 0; g < 8; ++g) {
      bool avail = ((gmask >> g) & 1u) == 0u;
      if (avail && gs[g] > best) { best = gs[g]; bi = g; }
    }
    gmask |= (1u << bi);
  }

  unsigned long long tm = 0ull;
#pragma unroll
  for (int g = 0; g < 8; ++g)
    if (((gmask >> g) & 1u) == 0u) tm |= (0xFFull << (8 * g));

  float wv[8]; int io[8]; float wsum = 0.f;
#pragma unroll
  for (int tsel = 0; tsel < 8; ++tsel) {
    float best = -__builtin_inff(); int bi = 0;
#pragma unroll
    for (int e = 0; e < E_N; ++e) {
      bool avail = ((tm >> e) & 1ull) == 0ull;
      if (avail && sb[e] > best) { best = sb[e]; bi = e; }
    }
    tm |= (1ull << bi);
    float sv = best - bl[bi];
    wv[tsel] = sv; io[tsel] = bi; wsum += sv;
  }

  const float scale = 2.5f / wsum;
  float4 w0 = make_float4(wv[0] * scale, wv[1] * scale, wv[2] * scale, wv[3] * scale);
  float4 w1 = make_float4(wv[4] * scale, wv[5] * scale, wv[6] * scale, wv[7] * scale);
  float4 i0 = make_float4((float)io[0], (float)io[1], (float)io[2], (float)io[3]);
  float4 i1 = make_float4((float)io[4], (float)io[5], (float)io[6], (float)io[7]);
  *(float4*)(out_w + (size_t)row * 8)     = w0;
  *(float4*)(out_w + (size_t)row * 8 + 4) = w1;
  *(float4*)(out_i + (size_t)row * 8)     = i0;
  *(float4*)(out_i + (size_t)row * 8 + 4) = i1;
}

extern "C" void kernel_launch(void* const* d_in, const int* in_sizes, int n_in,
                              void* d_out, int out_size, void* d_ws, size_t ws_size,
                              hipStream_t stream) {
  const float* x    = (const float*)d_in[0];
  const float* wgt  = (const float*)d_in[1];
  const float* bias = (const float*)d_in[2];
  float* out = (float*)d_out;
  unsigned short* wb = (unsigned short*)d_ws;
  float* logitsT = (float*)d_ws + WS_LOGITS_OFF;

  k_prep  <<<(E_N * KP) / 256, 256, 0, stream>>>(wgt, wb);
  k_logits<<<T_TOK / 64,       256, 0, stream>>>(x, wb, logitsT);
  k_route <<<T_TOK / 256,      256, 0, stream>>>(logitsT, bias,
                                                 out, out + (size_t)T_TOK * 8);
}

// Round 11
// 134.119 us; speedup vs baseline: 6.6172x; 1.8085x over previous
//
#include <hip/hip_runtime.h>
#include <math.h>

#define T_TOK 32768
#define DIM   2048
#define E_N   64
#define KP    2048   // padded K (k==0 column is zero)

typedef float v4f    __attribute__((ext_vector_type(4)));
typedef float f32x4  __attribute__((ext_vector_type(4)));
typedef short bf16x8 __attribute__((ext_vector_type(8)));
typedef unsigned int u32x4 __attribute__((ext_vector_type(4)));

// fragment-linear W: wl[kc][s][t][lane][8]  (64 kc x 3 s x 4 t x 64 lanes x 8)
#define CHUNK_USH 6144                    // ushorts per kc chunk (12 KB)
#define WL_USHORTS (64 * CHUNK_USH)       // 786432 B total
#define WS_LOGITS_OFF (WL_USHORTS / 2)    // float offset of logitsT in ws

__device__ __forceinline__ unsigned short rne16(unsigned u) {
  return (unsigned short)((u + 0x7fffu + ((u >> 16) & 1u)) >> 16);
}
__device__ __forceinline__ float bits2f(unsigned u) {
  union { unsigned u; float f; } c; c.u = u; return c.f;
}
__device__ __forceinline__ unsigned f2bits(float f) {
  union { float f; unsigned u; } c; c.f = f; return c.u;
}
__device__ __forceinline__ unsigned cvtpk(float a, float b) {  // lo=bf16(a), hi=bf16(b), RNE
  unsigned r;
  asm("v_cvt_pk_bf16_f32 %0, %1, %2" : "=v"(r) : "v"(a), "v"(b));
  return r;
}
__device__ __forceinline__ bf16x8 ldw(const unsigned short* p) {
  union { u32x4 u; bf16x8 b; } c; c.u = *(const u32x4*)p; return c.b;
}
__device__ __forceinline__ bf16x8 pack4(unsigned a, unsigned b, unsigned c, unsigned d) {
  union { u32x4 u; bf16x8 b; } t; t.u.x = a; t.u.y = b; t.u.z = c; t.u.w = d; return t.b;
}

// ---------------- kernel 0: W -> fragment-linear 3-way bf16 split ----------------
// wl[kc][s][t][lane][j]: expert e = t*16 + (lane&15), k = kc*32 + (lane>>4)*8 + j.
// Each MFMA A-fragment is then a CONTIGUOUS 1 KB block (lane i at +i*16B).
__global__ __launch_bounds__(256) void k_prep(const float* __restrict__ w,
                                              unsigned short* __restrict__ wl) {
  int idx = blockIdx.x * 256 + threadIdx.x;    // 0 .. 393215
  int kc = idx / CHUNK_USH;
  int r  = idx % CHUNK_USH;
  int s  = r >> 11;          // /2048
  int r2 = r & 2047;
  int t  = r2 >> 9;          // /512
  int r3 = r2 & 511;
  int lane = r3 >> 3;
  int j    = r3 & 7;
  int e = t * 16 + (lane & 15);
  int k = kc * 32 + (lane >> 4) * 8 + j;
  float f = (k == 0) ? 0.f : w[e * 2047 + (k - 1)];
  unsigned short b0 = rne16(f2bits(f));
  float r1v = f - bits2f((unsigned)b0 << 16);    // exact (Sterbenz)
  unsigned short b1 = rne16(f2bits(r1v));
  float r2v = r1v - bits2f((unsigned)b1 << 16);  // exact
  unsigned short b2 = rne16(f2bits(r2v));
  wl[idx] = (s == 0) ? b0 : (s == 1) ? b1 : b2;
}

// ---------------- kernel 1: logitsT[e][tok] via 6-pass bf16-split MFMA ----------------
// K-split 2: block = 4 waves = 2 token-tiles x 2 k-halves -> 4096 waves total
// = 4 waves/SIMD. W fragments are contiguous 1 KB loads (no stride pathology).
// Per-chunk math and MFMA pass order identical to the R10-passing kernel.
__global__ __launch_bounds__(256, 4) void k_logits(const float* __restrict__ x,
                                                   const unsigned short* __restrict__ wl,
                                                   float* __restrict__ logitsT) {
  __shared__ float red[2][4][4][64];   // [tt][t][r][lane] = 8 KB
  const int tid  = threadIdx.x;
  const int lane = tid & 63;
  const int l15  = lane & 15;
  const int w4   = tid >> 6;           // 0..3
  const int tt   = w4 & 1;             // token-tile within block
  const int kh   = w4 >> 1;            // k-half
  const int tok0 = (blockIdx.x * 2 + tt) * 16;

  const float* xr = x + (size_t)(tok0 + l15) * DIM + kh * 1024 + (lane >> 4) * 8;
  const unsigned short* wp = wl + (size_t)(kh * 32) * CHUNK_USH + lane * 8;

  f32x4 acc[4];
#pragma unroll
  for (int t = 0; t < 4; ++t) acc[t] = (f32x4)(0.f);

  v4f c0 = *(const v4f*)(xr);
  v4f c1 = *(const v4f*)(xr + 4);

  for (int c = 0; c < 32; ++c) {
    // 12 contiguous 1 KB fragment loads for this chunk
    bf16x8 wf[3][4];
    const unsigned short* wc = wp + c * CHUNK_USH;
#pragma unroll
    for (int s = 0; s < 3; ++s)
#pragma unroll
      for (int t = 0; t < 4; ++t)
        wf[s][t] = ldw(wc + (s * 4 + t) * 512);
    // x prefetch for next chunk (guarded, uniform condition)
    const float* nx = xr + ((c + 1 < 32) ? (c + 1) * 32 : 0);
    v4f n0 = *(const v4f*)(nx);
    v4f n1 = *(const v4f*)(nx + 4);
    // 3-way bf16 split of the 8 x values (residuals exact by Sterbenz)
    unsigned c00 = cvtpk(c0.x, c0.y), c01 = cvtpk(c0.z, c0.w);
    unsigned c02 = cvtpk(c1.x, c1.y), c03 = cvtpk(c1.z, c1.w);
    float r0 = c0.x - bits2f(c00 << 16), r1 = c0.y - bits2f(c00 & 0xFFFF0000u);
    float r2 = c0.z - bits2f(c01 << 16), r3 = c0.w - bits2f(c01 & 0xFFFF0000u);
    float r4 = c1.x - bits2f(c02 << 16), r5 = c1.y - bits2f(c02 & 0xFFFF0000u);
    float r6 = c1.z - bits2f(c03 << 16), r7 = c1.w - bits2f(c03 & 0xFFFF0000u);
    unsigned d0 = cvtpk(r0, r1), d1 = cvtpk(r2, r3);
    unsigned d2 = cvtpk(r4, r5), d3 = cvtpk(r6, r7);
    float s0 = r0 - bits2f(d0 << 16), s1 = r1 - bits2f(d0 & 0xFFFF0000u);
    float s2 = r2 - bits2f(d1 << 16), s3 = r3 - bits2f(d1 & 0xFFFF0000u);
    float s4 = r4 - bits2f(d2 << 16), s5 = r5 - bits2f(d2 & 0xFFFF0000u);
    float s6 = r6 - bits2f(d3 << 16), s7 = r7 - bits2f(d3 & 0xFFFF0000u);
    unsigned e0 = cvtpk(s0, s1), e1 = cvtpk(s2, s3);
    unsigned e2 = cvtpk(s4, s5), e3 = cvtpk(s6, s7);
    bf16x8 x0 = pack4(c00, c01, c02, c03);
    bf16x8 x1 = pack4(d0, d1, d2, d3);
    bf16x8 x2 = pack4(e0, e1, e2, e3);
    // 6 passes, smallest-magnitude first (identical order to R10)
#pragma unroll
    for (int t = 0; t < 4; ++t)
      acc[t] = __builtin_amdgcn_mfma_f32_16x16x32_bf16(wf[2][t], x0, acc[t], 0, 0, 0);
#pragma unroll
    for (int t = 0; t < 4; ++t)
      acc[t] = __builtin_amdgcn_mfma_f32_16x16x32_bf16(wf[1][t], x1, acc[t], 0, 0, 0);
#pragma unroll
    for (int t = 0; t < 4; ++t)
      acc[t] = __builtin_amdgcn_mfma_f32_16x16x32_bf16(wf[0][t], x2, acc[t], 0, 0, 0);
#pragma unroll
    for (int t = 0; t < 4; ++t)
      acc[t] = __builtin_amdgcn_mfma_f32_16x16x32_bf16(wf[1][t], x0, acc[t], 0, 0, 0);
#pragma unroll
    for (int t = 0; t < 4; ++t)
      acc[t] = __builtin_amdgcn_mfma_f32_16x16x32_bf16(wf[0][t], x1, acc[t], 0, 0, 0);
#pragma unroll
    for (int t = 0; t < 4; ++t)
      acc[t] = __builtin_amdgcn_mfma_f32_16x16x32_bf16(wf[0][t], x0, acc[t], 0, 0, 0);
    c0 = n0; c1 = n1;
  }

  // cross-k-half reduce: kh=1 writes partials, kh=0 adds and stores
  if (kh == 1) {
#pragma unroll
    for (int t = 0; t < 4; ++t)
#pragma unroll
      for (int r = 0; r < 4; ++r)
        red[tt][t][r][lane] = acc[t][r];   // lane-contiguous: conflict-free
  }
  __syncthreads();
  if (kh == 0) {
#pragma unroll
    for (int t = 0; t < 4; ++t)
#pragma unroll
      for (int r = 0; r < 4; ++r) {
        const float v = acc[t][r] + red[tt][t][r][lane];
        const int e = t * 16 + (lane >> 4) * 4 + r;
        logitsT[(size_t)e * T_TOK + tok0 + l15] = v;
      }
  }
}

// ---------------- kernel 2: per-row group-limited top-k routing ----------------
__global__ __launch_bounds__(256) void k_route(const float* __restrict__ logitsT,
                                               const float* __restrict__ bias,
                                               float* __restrict__ out_w,
                                               float* __restrict__ out_i) {
  __shared__ float bl[E_N];
  if (threadIdx.x < E_N) bl[threadIdx.x] = bias[threadIdx.x];
  __syncthreads();

  const int row = blockIdx.x * 256 + threadIdx.x;
  const float* lp = logitsT + row;                     // column access: coalesced

  float sb[E_N];
#pragma unroll
  for (int e = 0; e < E_N; ++e)
    sb[e] = 1.f / (1.f + expf(-lp[(size_t)e * T_TOK])) + bl[e];

  float gs[8];
#pragma unroll
  for (int g = 0; g < 8; ++g) {
    float m1 = -__builtin_inff(), m2 = -__builtin_inff();
#pragma unroll
    for (int j = 0; j < 8; ++j) {
      float v = sb[g * 8 + j];
      if (v > m1) { m2 = m1; m1 = v; }
      else if (v > m2) { m2 = v; }
    }
    gs[g] = m1 + m2;
  }

  unsigned gmask = 0;
#pragma unroll
  for (int tsel = 0; tsel < 4; ++tsel) {
    float best = -__builtin_inff(); int bi = 0;
#pragma unroll
    for (int g = 0; g < 8; ++g) {
      bool avail = ((gmask >> g) & 1u) == 0u;
      if (avail && gs[g] > best) { best = gs[g]; bi = g; }
    }
    gmask |= (1u << bi);
  }

  unsigned long long tm = 0ull;
#pragma unroll
  for (int g = 0; g < 8; ++g)
    if (((gmask >> g) & 1u) == 0u) tm |= (0xFFull << (8 * g));

  float wv[8]; int io[8]; float wsum = 0.f;
#pragma unroll
  for (int tsel = 0; tsel < 8; ++tsel) {
    float best = -__builtin_inff(); int bi = 0;
#pragma unroll
    for (int e = 0; e < E_N; ++e) {
      bool avail = ((tm >> e) & 1ull) == 0ull;
      if (avail && sb[e] > best) { best = sb[e]; bi = e; }
    }
    tm |= (1ull << bi);
    float sv = best - bl[bi];
    wv[tsel] = sv; io[tsel] = bi; wsum += sv;
  }

  const float scale = 2.5f / wsum;
  float4 w0 = make_float4(wv[0] * scale, wv[1] * scale, wv[2] * scale, wv[3] * scale);
  float4 w1 = make_float4(wv[4] * scale, wv[5] * scale, wv[6] * scale, wv[7] * scale);
  float4 i0 = make_float4((float)io[0], (float)io[1], (float)io[2], (float)io[3]);
  float4 i1 = make_float4((float)io[4], (float)io[5], (float)io[6], (float)io[7]);
  *(float4*)(out_w + (size_t)row * 8)     = w0;
  *(float4*)(out_w + (size_t)row * 8 + 4) = w1;
  *(float4*)(out_i + (size_t)row * 8)     = i0;
  *(float4*)(out_i + (size_t)row * 8 + 4) = i1;
}

extern "C" void kernel_launch(void* const* d_in, const int* in_sizes, int n_in,
                              void* d_out, int out_size, void* d_ws, size_t ws_size,
                              hipStream_t stream) {
  const float* x    = (const float*)d_in[0];
  const float* wgt  = (const float*)d_in[1];
  const float* bias = (const float*)d_in[2];
  float* out = (float*)d_out;
  unsigned short* wlp = (unsigned short*)d_ws;
  float* logitsT = (float*)d_ws + WS_LOGITS_OFF;

  k_prep  <<<WL_USHORTS / 256, 256, 0, stream>>>(wgt, wlp);
  k_logits<<<T_TOK / 32,       256, 0, stream>>>(x, wlp, logitsT);
  k_route <<<T_TOK / 256,      256, 0, stream>>>(logitsT, bias,
                                                 out, out + (size_t)T_TOK * 8);
}

// Round 12
// 110.714 us; speedup vs baseline: 8.0160x; 1.2114x over previous
//
#include <hip/hip_runtime.h>
#include <math.h>

#define T_TOK 32768
#define DIM   2048
#define E_N   64
#define KP    2048   // padded K (k==0 column is zero)

typedef float v4f    __attribute__((ext_vector_type(4)));
typedef float f32x4  __attribute__((ext_vector_type(4)));
typedef short bf16x8 __attribute__((ext_vector_type(8)));
typedef unsigned int u32x4 __attribute__((ext_vector_type(4)));

// fragment-linear W: wl[kc][s][t][lane][8]  (64 kc x 3 s x 4 t x 64 lanes x 8)
#define CHUNK_USH 6144                    // ushorts per kc chunk (12 KB)
#define WL_USHORTS (64 * CHUNK_USH)       // 786432 B total
#define WS_LOGITS_OFF (WL_USHORTS / 2)    // float offset of logitsT in ws

__device__ __forceinline__ unsigned short rne16(unsigned u) {
  return (unsigned short)((u + 0x7fffu + ((u >> 16) & 1u)) >> 16);
}
__device__ __forceinline__ float bits2f(unsigned u) {
  union { unsigned u; float f; } c; c.u = u; return c.f;
}
__device__ __forceinline__ unsigned f2bits(float f) {
  union { float f; unsigned u; } c; c.f = f; return c.u;
}
__device__ __forceinline__ unsigned cvtpk(float a, float b) {  // lo=bf16(a), hi=bf16(b), RNE
  unsigned r;
  asm("v_cvt_pk_bf16_f32 %0, %1, %2" : "=v"(r) : "v"(a), "v"(b));
  return r;
}
__device__ __forceinline__ bf16x8 ldw(const unsigned short* p) {
  union { u32x4 u; bf16x8 b; } c; c.u = *(const u32x4*)p; return c.b;
}
__device__ __forceinline__ bf16x8 pack4(unsigned a, unsigned b, unsigned c, unsigned d) {
  union { u32x4 u; bf16x8 b; } t; t.u.x = a; t.u.y = b; t.u.z = c; t.u.w = d; return t.b;
}
__device__ __forceinline__ void async16(const void* g, void* l) {
  __builtin_amdgcn_global_load_lds((const __attribute__((address_space(1))) void*)g,
                                   (__attribute__((address_space(3))) void*)l,
                                   16, 0, 0);
}

// ---------------- kernel 0: W -> fragment-linear 3-way bf16 split ----------------
// wl[kc][s][t][lane][j]: expert e = t*16 + (lane&15), k = kc*32 + (lane>>4)*8 + j.
__global__ __launch_bounds__(256) void k_prep(const float* __restrict__ w,
                                              unsigned short* __restrict__ wl) {
  int idx = blockIdx.x * 256 + threadIdx.x;    // 0 .. 393215
  int kc = idx / CHUNK_USH;
  int r  = idx % CHUNK_USH;
  int s  = r >> 11;          // /2048
  int r2 = r & 2047;
  int t  = r2 >> 9;          // /512
  int r3 = r2 & 511;
  int lane = r3 >> 3;
  int j    = r3 & 7;
  int e = t * 16 + (lane & 15);
  int k = kc * 32 + (lane >> 4) * 8 + j;
  float f = (k == 0) ? 0.f : w[e * 2047 + (k - 1)];
  unsigned short b0 = rne16(f2bits(f));
  float r1v = f - bits2f((unsigned)b0 << 16);    // exact (Sterbenz)
  unsigned short b1 = rne16(f2bits(r1v));
  float r2v = r1v - bits2f((unsigned)b1 << 16);  // exact
  unsigned short b2 = rne16(f2bits(r2v));
  wl[idx] = (s == 0) ? b0 : (s == 1) ? b1 : b2;
}

// ---------------- kernel 1: logitsT[e][tok] via 6-pass bf16-split MFMA ----------------
// Block = 4 waves x 16 tokens, FULL K per wave. W chunks (12 KB, fragment-
// linear) staged to LDS via global_load_lds, double-buffered; all 4 waves
// share each chunk (4x L2-traffic cut vs R11). x prefetched depth-2 in regs.
// Per-chunk math / MFMA order / output map identical to R10/R11 (verified).
__global__ __launch_bounds__(256) void k_logits(const float* __restrict__ x,
                                                const unsigned short* __restrict__ wl,
                                                float* __restrict__ logitsT) {
  __shared__ unsigned short wbuf[2][CHUNK_USH];   // 24 KB
  const int tid  = threadIdx.x;
  const int lane = tid & 63;
  const int l15  = lane & 15;
  const int tok0 = blockIdx.x * 64 + (tid >> 6) * 16;

  const float* xr = x + (size_t)(tok0 + l15) * DIM + (lane >> 4) * 8;

  auto stage = [&](int c, int b) {
#pragma unroll
    for (int i = 0; i < 3; ++i)
      async16(wl + (size_t)c * CHUNK_USH + (i * 256 + tid) * 8,
              &wbuf[b][(i * 256 + tid) * 8]);
  };

  f32x4 acc[4];
#pragma unroll
  for (int t = 0; t < 4; ++t) acc[t] = (f32x4)(0.f);

  // x slots: cur = chunk c, nxt = chunk c+1
  v4f xc0 = *(const v4f*)(xr);
  v4f xc1 = *(const v4f*)(xr + 4);
  v4f xn0 = *(const v4f*)(xr + 32);
  v4f xn1 = *(const v4f*)(xr + 36);

  stage(0, 0);
  asm volatile("s_waitcnt vmcnt(0)" ::: "memory");
  __syncthreads();

  for (int c = 0; c < 64; ++c) {
    const int cb = c & 1;
    if (c + 1 < 64) stage(c + 1, cb ^ 1);
    // x prefetch for c+2 (guarded; dummy reload of chunk 0 at the tail)
    const float* nx = xr + ((c + 2 < 64) ? (c + 2) * 32 : 0);
    v4f p0 = *(const v4f*)(nx);
    v4f p1 = *(const v4f*)(nx + 4);

    // 12 fragment reads from LDS (ds_read_b128, contiguous 1 KB each)
    bf16x8 wf[3][4];
#pragma unroll
    for (int s = 0; s < 3; ++s)
#pragma unroll
      for (int t = 0; t < 4; ++t)
        wf[s][t] = ldw(&wbuf[cb][(s * 4 + t) * 512 + lane * 8]);

    // 3-way bf16 split of the 8 x values (residuals exact by Sterbenz)
    unsigned c00 = cvtpk(xc0.x, xc0.y), c01 = cvtpk(xc0.z, xc0.w);
    unsigned c02 = cvtpk(xc1.x, xc1.y), c03 = cvtpk(xc1.z, xc1.w);
    float r0 = xc0.x - bits2f(c00 << 16), r1 = xc0.y - bits2f(c00 & 0xFFFF0000u);
    float r2 = xc0.z - bits2f(c01 << 16), r3 = xc0.w - bits2f(c01 & 0xFFFF0000u);
    float r4 = xc1.x - bits2f(c02 << 16), r5 = xc1.y - bits2f(c02 & 0xFFFF0000u);
    float r6 = xc1.z - bits2f(c03 << 16), r7 = xc1.w - bits2f(c03 & 0xFFFF0000u);
    unsigned d0 = cvtpk(r0, r1), d1 = cvtpk(r2, r3);
    unsigned d2 = cvtpk(r4, r5), d3 = cvtpk(r6, r7);
    float s0 = r0 - bits2f(d0 << 16), s1 = r1 - bits2f(d0 & 0xFFFF0000u);
    float s2 = r2 - bits2f(d1 << 16), s3 = r3 - bits2f(d1 & 0xFFFF0000u);
    float s4 = r4 - bits2f(d2 << 16), s5 = r5 - bits2f(d2 & 0xFFFF0000u);
    float s6 = r6 - bits2f(d3 << 16), s7 = r7 - bits2f(d3 & 0xFFFF0000u);
    unsigned e0 = cvtpk(s0, s1), e1 = cvtpk(s2, s3);
    unsigned e2 = cvtpk(s4, s5), e3 = cvtpk(s6, s7);
    bf16x8 x0 = pack4(c00, c01, c02, c03);
    bf16x8 x1 = pack4(d0, d1, d2, d3);
    bf16x8 x2 = pack4(e0, e1, e2, e3);

    // 6 passes, smallest-magnitude first (identical order to R10/R11)
#pragma unroll
    for (int t = 0; t < 4; ++t)
      acc[t] = __builtin_amdgcn_mfma_f32_16x16x32_bf16(wf[2][t], x0, acc[t], 0, 0, 0);
#pragma unroll
    for (int t = 0; t < 4; ++t)
      acc[t] = __builtin_amdgcn_mfma_f32_16x16x32_bf16(wf[1][t], x1, acc[t], 0, 0, 0);
#pragma unroll
    for (int t = 0; t < 4; ++t)
      acc[t] = __builtin_amdgcn_mfma_f32_16x16x32_bf16(wf[0][t], x2, acc[t], 0, 0, 0);
#pragma unroll
    for (int t = 0; t < 4; ++t)
      acc[t] = __builtin_amdgcn_mfma_f32_16x16x32_bf16(wf[1][t], x0, acc[t], 0, 0, 0);
#pragma unroll
    for (int t = 0; t < 4; ++t)
      acc[t] = __builtin_amdgcn_mfma_f32_16x16x32_bf16(wf[0][t], x1, acc[t], 0, 0, 0);
#pragma unroll
    for (int t = 0; t < 4; ++t)
      acc[t] = __builtin_amdgcn_mfma_f32_16x16x32_bf16(wf[0][t], x0, acc[t], 0, 0, 0);

    xc0 = xn0; xc1 = xn1; xn0 = p0; xn1 = p1;

    asm volatile("s_waitcnt vmcnt(0)" ::: "memory");   // next chunk staged
    __syncthreads();                                    // + all reads of cb done
  }

  // D: expert = t*16 + (lane>>4)*4 + r, token = tok0 + l15 -> coalesced
#pragma unroll
  for (int t = 0; t < 4; ++t)
#pragma unroll
    for (int r = 0; r < 4; ++r) {
      const int e = t * 16 + (lane >> 4) * 4 + r;
      logitsT[(size_t)e * T_TOK + tok0 + l15] = acc[t][r];
    }
}

// ---------------- kernel 2: per-row group-limited top-k routing ----------------
__global__ __launch_bounds__(256) void k_route(const float* __restrict__ logitsT,
                                               const float* __restrict__ bias,
                                               float* __restrict__ out_w,
                                               float* __restrict__ out_i) {
  __shared__ float bl[E_N];
  if (threadIdx.x < E_N) bl[threadIdx.x] = bias[threadIdx.x];
  __syncthreads();

  const int row = blockIdx.x * 256 + threadIdx.x;
  const float* lp = logitsT + row;                     // column access: coalesced

  float sb[E_N];
#pragma unroll
  for (int e = 0; e < E_N; ++e)
    sb[e] = 1.f / (1.f + expf(-lp[(size_t)e * T_TOK])) + bl[e];

  float gs[8];
#pragma unroll
  for (int g = 0; g < 8; ++g) {
    float m1 = -__builtin_inff(), m2 = -__builtin_inff();
#pragma unroll
    for (int j = 0; j < 8; ++j) {
      float v = sb[g * 8 + j];
      if (v > m1) { m2 = m1; m1 = v; }
      else if (v > m2) { m2 = v; }
    }
    gs[g] = m1 + m2;
  }

  unsigned gmask = 0;
#pragma unroll
  for (int tsel = 0; tsel < 4; ++tsel) {
    float best = -__builtin_inff(); int bi = 0;
#pragma unroll
    for (int g = 0; g < 8; ++g) {
      bool avail = ((gmask >> g) & 1u) == 0u;
      if (avail && gs[g] > best) { best = gs[g]; bi = g; }
    }
    gmask |= (1u << bi);
  }

  unsigned long long tm = 0ull;
#pragma unroll
  for (int g = 0; g < 8; ++g)
    if (((gmask >> g) & 1u) == 0u) tm |= (0xFFull << (8 * g));

  float wv[8]; int io[8]; float wsum = 0.f;
#pragma unroll
  for (int tsel = 0; tsel < 8; ++tsel) {
    float best = -__builtin_inff(); int bi = 0;
#pragma unroll
    for (int e = 0; e < E_N; ++e) {
      bool avail = ((tm >> e) & 1ull) == 0ull;
      if (avail && sb[e] > best) { best = sb[e]; bi = e; }
    }
    tm |= (1ull << bi);
    float sv = best - bl[bi];
    wv[tsel] = sv; io[tsel] = bi; wsum += sv;
  }

  const float scale = 2.5f / wsum;
  float4 w0 = make_float4(wv[0] * scale, wv[1] * scale, wv[2] * scale, wv[3] * scale);
  float4 w1 = make_float4(wv[4] * scale, wv[5] * scale, wv[6] * scale, wv[7] * scale);
  float4 i0 = make_float4((float)io[0], (float)io[1], (float)io[2], (float)io[3]);
  float4 i1 = make_float4((float)io[4], (float)io[5], (float)io[6], (float)io[7]);
  *(float4*)(out_w + (size_t)row * 8)     = w0;
  *(float4*)(out_w + (size_t)row * 8 + 4) = w1;
  *(float4*)(out_i + (size_t)row * 8)     = i0;
  *(float4*)(out_i + (size_t)row * 8 + 4) = i1;
}

extern "C" void kernel_launch(void* const* d_in, const int* in_sizes, int n_in,
                              void* d_out, int out_size, void* d_ws, size_t ws_size,
                              hipStream_t stream) {
  const float* x    = (const float*)d_in[0];
  const float* wgt  = (const float*)d_in[1];
  const float* bias = (const float*)d_in[2];
  float* out = (float*)d_out;
  unsigned short* wlp = (unsigned short*)d_ws;
  float* logitsT = (float*)d_ws + WS_LOGITS_OFF;

  k_prep  <<<WL_USHORTS / 256, 256, 0, stream>>>(wgt, wlp);
  k_logits<<<T_TOK / 64,       256, 0, stream>>>(x, wlp, logitsT);
  k_route <<<T_TOK / 256,      256, 0, stream>>>(logitsT, bias,
                                                 out, out + (size_t)T_TOK * 8);
}

// Round 13
// 92.882 us; speedup vs baseline: 9.5551x; 1.1920x over previous
//
#include <hip/hip_runtime.h>
#include <math.h>

#define T_TOK 32768
#define DIM   2048
#define E_N   64
#define KP    2048   // padded K (k==0 column is zero)

typedef float v4f    __attribute__((ext_vector_type(4)));
typedef float f32x4  __attribute__((ext_vector_type(4)));
typedef short bf16x8 __attribute__((ext_vector_type(8)));
typedef unsigned int u32x4 __attribute__((ext_vector_type(4)));

// fragment-linear W: wl[kc][s][t][lane][8]  (64 kc x 3 s x 4 t x 64 lanes x 8)
#define CHUNK_USH 6144                    // ushorts per kc chunk (12 KB)
#define WL_USHORTS (64 * CHUNK_USH)       // 786432 B total
#define WS_LOGITS_OFF (WL_USHORTS / 2)    // float offset of logitsT in ws

__device__ __forceinline__ unsigned short rne16(unsigned u) {
  return (unsigned short)((u + 0x7fffu + ((u >> 16) & 1u)) >> 16);
}
__device__ __forceinline__ float bits2f(unsigned u) {
  union { unsigned u; float f; } c; c.u = u; return c.f;
}
__device__ __forceinline__ unsigned f2bits(float f) {
  union { float f; unsigned u; } c; c.f = f; return c.u;
}
__device__ __forceinline__ unsigned cvtpk(float a, float b) {  // lo=bf16(a), hi=bf16(b), RNE
  unsigned r;
  asm("v_cvt_pk_bf16_f32 %0, %1, %2" : "=v"(r) : "v"(a), "v"(b));
  return r;
}
__device__ __forceinline__ bf16x8 ldw(const unsigned short* p) {
  union { u32x4 u; bf16x8 b; } c; c.u = *(const u32x4*)p; return c.b;
}
__device__ __forceinline__ bf16x8 pack4(unsigned a, unsigned b, unsigned c, unsigned d) {
  union { u32x4 u; bf16x8 b; } t; t.u.x = a; t.u.y = b; t.u.z = c; t.u.w = d; return t.b;
}
__device__ __forceinline__ void async16(const void* g, void* l) {
  __builtin_amdgcn_global_load_lds((const __attribute__((address_space(1))) void*)g,
                                   (__attribute__((address_space(3))) void*)l,
                                   16, 0, 0);
}

// ---------------- kernel 0: W -> fragment-linear 3-way bf16 split ----------------
// wl[kc][s][t][lane][j]: expert e = t*16 + (lane&15), k = kc*32 + (lane>>4)*8 + j.
__global__ __launch_bounds__(256) void k_prep(const float* __restrict__ w,
                                              unsigned short* __restrict__ wl) {
  int idx = blockIdx.x * 256 + threadIdx.x;    // 0 .. 393215
  int kc = idx / CHUNK_USH;
  int r  = idx % CHUNK_USH;
  int s  = r >> 11;          // /2048
  int r2 = r & 2047;
  int t  = r2 >> 9;          // /512
  int r3 = r2 & 511;
  int lane = r3 >> 3;
  int j    = r3 & 7;
  int e = t * 16 + (lane & 15);
  int k = kc * 32 + (lane >> 4) * 8 + j;
  float f = (k == 0) ? 0.f : w[e * 2047 + (k - 1)];
  unsigned short b0 = rne16(f2bits(f));
  float r1v = f - bits2f((unsigned)b0 << 16);    // exact (Sterbenz)
  unsigned short b1 = rne16(f2bits(r1v));
  float r2v = r1v - bits2f((unsigned)b1 << 16);  // exact
  unsigned short b2 = rne16(f2bits(r2v));
  wl[idx] = (s == 0) ? b0 : (s == 1) ? b1 : b2;
}

// ---------------- kernel 1: logitsT[e][tok] via 6-pass bf16-split MFMA ----------------
// Block = 8 waves = 4 token-tiles (tt) x 2 k-halves (kh); 512 blocks x 2/CU
// -> 16 waves/CU = 4/SIMD. Each step stages the chunk PAIR (c, c+32) = 24 KB
// double-buffered; threads<256 stage kh=0, >=256 stage kh=1. Per-wave inner
// loop (12 LDS fragment reads + 3-way x split + 6-pass MFMA) identical to the
// R10-R12-verified kernel. kh=1 partials reduced via LDS (R11 pattern).
__global__ __launch_bounds__(512, 4) void k_logits(const float* __restrict__ x,
                                                   const unsigned short* __restrict__ wl,
                                                   float* __restrict__ logitsT) {
  __shared__ union ShMem {
    unsigned short wbuf[2][2][CHUNK_USH];   // [buf][kh][..] 48 KB
    float red[4][4][4][64];                 // [tt][t][r][lane] 16 KB (epilogue)
  } sh;
  const int tid  = threadIdx.x;
  const int lane = tid & 63;
  const int l15  = lane & 15;
  const int w8   = tid >> 6;           // 0..7
  const int tt   = w8 & 3;             // token-tile
  const int kh   = w8 >> 2;            // k-half
  const int tok0 = blockIdx.x * 64 + tt * 16;

  const float* xr = x + (size_t)(tok0 + l15) * DIM + kh * 1024 + (lane >> 4) * 8;

  // staging: half = tid>>8 stages chunk (c + half*32); lane-linear 16B dest
  const int half = tid >> 8;
  const int t256 = tid & 255;
  auto stage = [&](int c, int b) {
    const unsigned short* src = wl + (size_t)(c + half * 32) * CHUNK_USH;
#pragma unroll
    for (int i = 0; i < 3; ++i)
      async16(src + (i * 256 + t256) * 8, &sh.wbuf[b][half][(i * 256 + t256) * 8]);
  };

  f32x4 acc[4];
#pragma unroll
  for (int t = 0; t < 4; ++t) acc[t] = (f32x4)(0.f);

  // x slots: cur = step c, nxt = step c+1
  v4f xc0 = *(const v4f*)(xr);
  v4f xc1 = *(const v4f*)(xr + 4);
  v4f xn0 = *(const v4f*)(xr + 32);
  v4f xn1 = *(const v4f*)(xr + 36);

  stage(0, 0);
  asm volatile("s_waitcnt vmcnt(0)" ::: "memory");
  __syncthreads();

  for (int c = 0; c < 32; ++c) {
    const int cb = c & 1;
    if (c + 1 < 32) stage(c + 1, cb ^ 1);
    // x prefetch for c+2 (guarded; dummy reload at the tail)
    const float* nx = xr + ((c + 2 < 32) ? (c + 2) * 32 : 0);
    v4f p0 = *(const v4f*)(nx);
    v4f p1 = *(const v4f*)(nx + 4);

    // 12 fragment reads from this wave's k-half (ds_read_b128, 1 KB each)
    bf16x8 wf[3][4];
#pragma unroll
    for (int s = 0; s < 3; ++s)
#pragma unroll
      for (int t = 0; t < 4; ++t)
        wf[s][t] = ldw(&sh.wbuf[cb][kh][(s * 4 + t) * 512 + lane * 8]);

    // 3-way bf16 split of the 8 x values (residuals exact by Sterbenz)
    unsigned c00 = cvtpk(xc0.x, xc0.y), c01 = cvtpk(xc0.z, xc0.w);
    unsigned c02 = cvtpk(xc1.x, xc1.y), c03 = cvtpk(xc1.z, xc1.w);
    float r0 = xc0.x - bits2f(c00 << 16), r1 = xc0.y - bits2f(c00 & 0xFFFF0000u);
    float r2 = xc0.z - bits2f(c01 << 16), r3 = xc0.w - bits2f(c01 & 0xFFFF0000u);
    float r4 = xc1.x - bits2f(c02 << 16), r5 = xc1.y - bits2f(c02 & 0xFFFF0000u);
    float r6 = xc1.z - bits2f(c03 << 16), r7 = xc1.w - bits2f(c03 & 0xFFFF0000u);
    unsigned d0 = cvtpk(r0, r1), d1 = cvtpk(r2, r3);
    unsigned d2 = cvtpk(r4, r5), d3 = cvtpk(r6, r7);
    float s0 = r0 - bits2f(d0 << 16), s1 = r1 - bits2f(d0 & 0xFFFF0000u);
    float s2 = r2 - bits2f(d1 << 16), s3 = r3 - bits2f(d1 & 0xFFFF0000u);
    float s4 = r4 - bits2f(d2 << 16), s5 = r5 - bits2f(d2 & 0xFFFF0000u);
    float s6 = r6 - bits2f(d3 << 16), s7 = r7 - bits2f(d3 & 0xFFFF0000u);
    unsigned e0 = cvtpk(s0, s1), e1 = cvtpk(s2, s3);
    unsigned e2 = cvtpk(s4, s5), e3 = cvtpk(s6, s7);
    bf16x8 x0 = pack4(c00, c01, c02, c03);
    bf16x8 x1 = pack4(d0, d1, d2, d3);
    bf16x8 x2 = pack4(e0, e1, e2, e3);

    // 6 passes, smallest-magnitude first (identical order to R10-R12)
#pragma unroll
    for (int t = 0; t < 4; ++t)
      acc[t] = __builtin_amdgcn_mfma_f32_16x16x32_bf16(wf[2][t], x0, acc[t], 0, 0, 0);
#pragma unroll
    for (int t = 0; t < 4; ++t)
      acc[t] = __builtin_amdgcn_mfma_f32_16x16x32_bf16(wf[1][t], x1, acc[t], 0, 0, 0);
#pragma unroll
    for (int t = 0; t < 4; ++t)
      acc[t] = __builtin_amdgcn_mfma_f32_16x16x32_bf16(wf[0][t], x2, acc[t], 0, 0, 0);
#pragma unroll
    for (int t = 0; t < 4; ++t)
      acc[t] = __builtin_amdgcn_mfma_f32_16x16x32_bf16(wf[1][t], x0, acc[t], 0, 0, 0);
#pragma unroll
    for (int t = 0; t < 4; ++t)
      acc[t] = __builtin_amdgcn_mfma_f32_16x16x32_bf16(wf[0][t], x1, acc[t], 0, 0, 0);
#pragma unroll
    for (int t = 0; t < 4; ++t)
      acc[t] = __builtin_amdgcn_mfma_f32_16x16x32_bf16(wf[0][t], x0, acc[t], 0, 0, 0);

    xc0 = xn0; xc1 = xn1; xn0 = p0; xn1 = p1;

    asm volatile("s_waitcnt vmcnt(0)" ::: "memory");   // next pair staged
    __syncthreads();                                    // + all reads of cb done
  }

  // cross-k-half reduce: kh=1 writes partials, kh=0 adds and stores
  if (kh == 1) {
#pragma unroll
    for (int t = 0; t < 4; ++t)
#pragma unroll
      for (int r = 0; r < 4; ++r)
        sh.red[tt][t][r][lane] = acc[t][r];   // lane-contiguous: conflict-free
  }
  __syncthreads();
  if (kh == 0) {
#pragma unroll
    for (int t = 0; t < 4; ++t)
#pragma unroll
      for (int r = 0; r < 4; ++r) {
        const float v = acc[t][r] + sh.red[tt][t][r][lane];
        const int e = t * 16 + (lane >> 4) * 4 + r;
        logitsT[(size_t)e * T_TOK + tok0 + l15] = v;
      }
  }
}

// ---------------- kernel 2: per-row group-limited top-k routing ----------------
__global__ __launch_bounds__(256) void k_route(const float* __restrict__ logitsT,
                                               const float* __restrict__ bias,
                                               float* __restrict__ out_w,
                                               float* __restrict__ out_i) {
  __shared__ float bl[E_N];
  if (threadIdx.x < E_N) bl[threadIdx.x] = bias[threadIdx.x];
  __syncthreads();

  const int row = blockIdx.x * 256 + threadIdx.x;
  const float* lp = logitsT + row;                     // column access: coalesced

  float sb[E_N];
#pragma unroll
  for (int e = 0; e < E_N; ++e)
    sb[e] = 1.f / (1.f + expf(-lp[(size_t)e * T_TOK])) + bl[e];

  float gs[8];
#pragma unroll
  for (int g = 0; g < 8; ++g) {
    float m1 = -__builtin_inff(), m2 = -__builtin_inff();
#pragma unroll
    for (int j = 0; j < 8; ++j) {
      float v = sb[g * 8 + j];
      if (v > m1) { m2 = m1; m1 = v; }
      else if (v > m2) { m2 = v; }
    }
    gs[g] = m1 + m2;
  }

  unsigned gmask = 0;
#pragma unroll
  for (int tsel = 0; tsel < 4; ++tsel) {
    float best = -__builtin_inff(); int bi = 0;
#pragma unroll
    for (int g = 0; g < 8; ++g) {
      bool avail = ((gmask >> g) & 1u) == 0u;
      if (avail && gs[g] > best) { best = gs[g]; bi = g; }
    }
    gmask |= (1u << bi);
  }

  unsigned long long tm = 0ull;
#pragma unroll
  for (int g = 0; g < 8; ++g)
    if (((gmask >> g) & 1u) == 0u) tm |= (0xFFull << (8 * g));

  float wv[8]; int io[8]; float wsum = 0.f;
#pragma unroll
  for (int tsel = 0; tsel < 8; ++tsel) {
    float best = -__builtin_inff(); int bi = 0;
#pragma unroll
    for (int e = 0; e < E_N; ++e) {
      bool avail = ((tm >> e) & 1ull) == 0ull;
      if (avail && sb[e] > best) { best = sb[e]; bi = e; }
    }
    tm |= (1ull << bi);
    float sv = best - bl[bi];
    wv[tsel] = sv; io[tsel] = bi; wsum += sv;
  }

  const float scale = 2.5f / wsum;
  float4 w0 = make_float4(wv[0] * scale, wv[1] * scale, wv[2] * scale, wv[3] * scale);
  float4 w1 = make_float4(wv[4] * scale, wv[5] * scale, wv[6] * scale, wv[7] * scale);
  float4 i0 = make_float4((float)io[0], (float)io[1], (float)io[2], (float)io[3]);
  float4 i1 = make_float4((float)io[4], (float)io[5], (float)io[6], (float)io[7]);
  *(float4*)(out_w + (size_t)row * 8)     = w0;
  *(float4*)(out_w + (size_t)row * 8 + 4) = w1;
  *(float4*)(out_i + (size_t)row * 8)     = i0;
  *(float4*)(out_i + (size_t)row * 8 + 4) = i1;
}

extern "C" void kernel_launch(void* const* d_in, const int* in_sizes, int n_in,
                              void* d_out, int out_size, void* d_ws, size_t ws_size,
                              hipStream_t stream) {
  const float* x    = (const float*)d_in[0];
  const float* wgt  = (const float*)d_in[1];
  const float* bias = (const float*)d_in[2];
  float* out = (float*)d_out;
  unsigned short* wlp = (unsigned short*)d_ws;
  float* logitsT = (float*)d_ws + WS_LOGITS_OFF;

  k_prep  <<<WL_USHORTS / 256, 256, 0, stream>>>(wgt, wlp);
  k_logits<<<T_TOK / 64,       512, 0, stream>>>(x, wlp, logitsT);
  k_route <<<T_TOK / 256,      256, 0, stream>>>(logitsT, bias,
                                                 out, out + (size_t)T_TOK * 8);
}

// Round 14
// 82.784 us; speedup vs baseline: 10.7206x; 1.1220x over previous
//
#include <hip/hip_runtime.h>
#include <math.h>

#define T_TOK 32768
#define DIM   2048
#define E_N   64
#define KP    2048   // padded K (k==0 column is zero)

typedef float v4f    __attribute__((ext_vector_type(4)));
typedef float f32x4  __attribute__((ext_vector_type(4)));
typedef short bf16x8 __attribute__((ext_vector_type(8)));
typedef unsigned int u32x4 __attribute__((ext_vector_type(4)));

// fragment-linear W: wl[kc][s][t][lane][8]  (64 kc x 3 s x 4 t x 64 lanes x 8)
#define CHUNK_USH 6144                    // ushorts per kc chunk (12 KB)
#define WL_USHORTS (64 * CHUNK_USH)       // 786432 B total

__device__ __forceinline__ unsigned short rne16(unsigned u) {
  return (unsigned short)((u + 0x7fffu + ((u >> 16) & 1u)) >> 16);
}
__device__ __forceinline__ float bits2f(unsigned u) {
  union { unsigned u; float f; } c; c.u = u; return c.f;
}
__device__ __forceinline__ unsigned f2bits(float f) {
  union { float f; unsigned u; } c; c.f = f; return c.u;
}
__device__ __forceinline__ unsigned cvtpk(float a, float b) {  // lo=bf16(a), hi=bf16(b), RNE
  unsigned r;
  asm("v_cvt_pk_bf16_f32 %0, %1, %2" : "=v"(r) : "v"(a), "v"(b));
  return r;
}
__device__ __forceinline__ bf16x8 ldw(const unsigned short* p) {
  union { u32x4 u; bf16x8 b; } c; c.u = *(const u32x4*)p; return c.b;
}
__device__ __forceinline__ bf16x8 pack4(unsigned a, unsigned b, unsigned c, unsigned d) {
  union { u32x4 u; bf16x8 b; } t; t.u.x = a; t.u.y = b; t.u.z = c; t.u.w = d; return t.b;
}
__device__ __forceinline__ void async16(const void* g, void* l) {
  __builtin_amdgcn_global_load_lds((const __attribute__((address_space(1))) void*)g,
                                   (__attribute__((address_space(3))) void*)l,
                                   16, 0, 0);
}

// ---------------- kernel 0: W -> fragment-linear 3-way bf16 split ----------------
// wl[kc][s][t][lane][j]: expert e = t*16 + (lane&15), k = kc*32 + (lane>>4)*8 + j.
__global__ __launch_bounds__(256) void k_prep(const float* __restrict__ w,
                                              unsigned short* __restrict__ wl) {
  int idx = blockIdx.x * 256 + threadIdx.x;    // 0 .. 393215
  int kc = idx / CHUNK_USH;
  int r  = idx % CHUNK_USH;
  int s  = r >> 11;          // /2048
  int r2 = r & 2047;
  int t  = r2 >> 9;          // /512
  int r3 = r2 & 511;
  int lane = r3 >> 3;
  int j    = r3 & 7;
  int e = t * 16 + (lane & 15);
  int k = kc * 32 + (lane >> 4) * 8 + j;
  float f = (k == 0) ? 0.f : w[e * 2047 + (k - 1)];
  unsigned short b0 = rne16(f2bits(f));
  float r1v = f - bits2f((unsigned)b0 << 16);    // exact (Sterbenz)
  unsigned short b1 = rne16(f2bits(r1v));
  float r2v = r1v - bits2f((unsigned)b1 << 16);  // exact
  unsigned short b2 = rne16(f2bits(r2v));
  wl[idx] = (s == 0) ? b0 : (s == 1) ? b1 : b2;
}

// ---------------- kernel 1: fused logits + routing ----------------
// Block = 8 waves = 4 token-tiles (tt) x 2 k-halves (kh); 512 blocks, 2/CU ->
// 16 waves/CU = 4 waves/SIMD. W chunk pairs staged to LDS (double-buffered),
// x prefetched at 2-STEP distance (unroll-2, reload-into-consumed-slot), and
// counted vmcnt(2) leaves x loads in flight across barriers. Per-chunk math /
// MFMA order identical to the R10-R13-verified kernel. Epilogue: kh-reduce ->
// logits to LDS -> per-token group-limited top-k (identical to R13 k_route)
// -> direct out_w/out_i stores. No logits round-trip, no third kernel.
__global__ __launch_bounds__(512, 4) void k_logits(const float* __restrict__ x,
                                                   const unsigned short* __restrict__ wl,
                                                   const float* __restrict__ bias,
                                                   float* __restrict__ out_w,
                                                   float* __restrict__ out_i) {
  __shared__ union ShMem {
    unsigned short wbuf[2][2][CHUNK_USH];   // [buf][kh][..] 48 KB
    struct { float red[4][4][4][64]; float lgt[E_N][65]; } ep;  // 16 KB + 16.6 KB
  } sh;
  const int tid  = threadIdx.x;
  const int lane = tid & 63;
  const int l15  = lane & 15;
  const int w8   = tid >> 6;           // 0..7
  const int tt   = w8 & 3;             // token-tile
  const int kh   = w8 >> 2;            // k-half
  const int tok0 = blockIdx.x * 64 + tt * 16;

  const float* xr = x + (size_t)(tok0 + l15) * DIM + kh * 1024 + (lane >> 4) * 8;

  // staging: half = tid>>8 stages chunk (c + half*32); lane-linear 16B dest
  const int half = tid >> 8;
  const int t256 = tid & 255;
  auto stage = [&](int c, int b) {
    const unsigned short* src = wl + (size_t)(c + half * 32) * CHUNK_USH;
#pragma unroll
    for (int i = 0; i < 3; ++i)
      async16(src + (i * 256 + t256) * 8, &sh.wbuf[b][half][(i * 256 + t256) * 8]);
  };

  f32x4 acc[4];
#pragma unroll
  for (int t = 0; t < 4; ++t) acc[t] = (f32x4)(0.f);

  // one step: split slot (s0,s1) -> reload slot for chunk xc -> LDS frags ->
  // 6-pass MFMA -> vmcnt(2) + barrier. rb = LDS read buf, sc/sb = stage args.
  auto step = [&](v4f& s0, v4f& s1, int rb, int sc, int sb, int xc) {
    if (sc < 32) stage(sc, sb);
    // 3-way bf16 split of the 8 x values (residuals exact by Sterbenz)
    unsigned c00 = cvtpk(s0.x, s0.y), c01 = cvtpk(s0.z, s0.w);
    unsigned c02 = cvtpk(s1.x, s1.y), c03 = cvtpk(s1.z, s1.w);
    float r0 = s0.x - bits2f(c00 << 16), r1 = s0.y - bits2f(c00 & 0xFFFF0000u);
    float r2 = s0.z - bits2f(c01 << 16), r3 = s0.w - bits2f(c01 & 0xFFFF0000u);
    float r4 = s1.x - bits2f(c02 << 16), r5 = s1.y - bits2f(c02 & 0xFFFF0000u);
    float r6 = s1.z - bits2f(c03 << 16), r7 = s1.w - bits2f(c03 & 0xFFFF0000u);
    unsigned d0 = cvtpk(r0, r1), d1 = cvtpk(r2, r3);
    unsigned d2 = cvtpk(r4, r5), d3 = cvtpk(r6, r7);
    float s0v = r0 - bits2f(d0 << 16), s1v = r1 - bits2f(d0 & 0xFFFF0000u);
    float s2v = r2 - bits2f(d1 << 16), s3v = r3 - bits2f(d1 & 0xFFFF0000u);
    float s4v = r4 - bits2f(d2 << 16), s5v = r5 - bits2f(d2 & 0xFFFF0000u);
    float s6v = r6 - bits2f(d3 << 16), s7v = r7 - bits2f(d3 & 0xFFFF0000u);
    unsigned e0 = cvtpk(s0v, s1v), e1 = cvtpk(s2v, s3v);
    unsigned e2 = cvtpk(s4v, s5v), e3 = cvtpk(s6v, s7v);
    bf16x8 x0 = pack4(c00, c01, c02, c03);
    bf16x8 x1 = pack4(d0, d1, d2, d3);
    bf16x8 x2 = pack4(e0, e1, e2, e3);
    // slot is dead now: reload it for chunk xc (2-step distance; dummy at tail)
    const float* nx = xr + ((xc < 32) ? xc * 32 : 0);
    s0 = *(const v4f*)(nx);
    s1 = *(const v4f*)(nx + 4);
    // 12 fragment reads from this wave's k-half (ds_read_b128, 1 KB each)
    bf16x8 wf[3][4];
#pragma unroll
    for (int s = 0; s < 3; ++s)
#pragma unroll
      for (int t = 0; t < 4; ++t)
        wf[s][t] = ldw(&sh.wbuf[rb][kh][(s * 4 + t) * 512 + lane * 8]);
    // 6 passes, smallest-magnitude first (identical order to R10-R13)
#pragma unroll
    for (int t = 0; t < 4; ++t)
      acc[t] = __builtin_amdgcn_mfma_f32_16x16x32_bf16(wf[2][t], x0, acc[t], 0, 0, 0);
#pragma unroll
    for (int t = 0; t < 4; ++t)
      acc[t] = __builtin_amdgcn_mfma_f32_16x16x32_bf16(wf[1][t], x1, acc[t], 0, 0, 0);
#pragma unroll
    for (int t = 0; t < 4; ++t)
      acc[t] = __builtin_amdgcn_mfma_f32_16x16x32_bf16(wf[0][t], x2, acc[t], 0, 0, 0);
#pragma unroll
    for (int t = 0; t < 4; ++t)
      acc[t] = __builtin_amdgcn_mfma_f32_16x16x32_bf16(wf[1][t], x0, acc[t], 0, 0, 0);
#pragma unroll
    for (int t = 0; t < 4; ++t)
      acc[t] = __builtin_amdgcn_mfma_f32_16x16x32_bf16(wf[0][t], x1, acc[t], 0, 0, 0);
#pragma unroll
    for (int t = 0; t < 4; ++t)
      acc[t] = __builtin_amdgcn_mfma_f32_16x16x32_bf16(wf[0][t], x0, acc[t], 0, 0, 0);
    // wait W-stage only (newest 2 outstanding = this step's x loads stay in flight)
    asm volatile("s_waitcnt vmcnt(2)" ::: "memory");
    __syncthreads();
  };

  // x slots: a = even chunks, b = odd chunks (2-step issue-to-use distance)
  v4f a0 = *(const v4f*)(xr);
  v4f a1 = *(const v4f*)(xr + 4);
  v4f b0 = *(const v4f*)(xr + 32);
  v4f b1 = *(const v4f*)(xr + 36);

  stage(0, 0);
  asm volatile("s_waitcnt vmcnt(0)" ::: "memory");
  __syncthreads();

  for (int cc = 0; cc < 32; cc += 2) {
    step(a0, a1, 0, cc + 1, 1, cc + 2);   // chunk cc   (reads buf0)
    step(b0, b1, 1, cc + 2, 0, cc + 3);   // chunk cc+1 (reads buf1)
  }

  // ---- epilogue: kh-reduce, logits -> LDS, fused routing ----
  if (kh == 1) {
#pragma unroll
    for (int t = 0; t < 4; ++t)
#pragma unroll
      for (int r = 0; r < 4; ++r)
        sh.ep.red[tt][t][r][lane] = acc[t][r];   // lane-contiguous: conflict-free
  }
  __syncthreads();
  if (kh == 0) {
#pragma unroll
    for (int t = 0; t < 4; ++t)
#pragma unroll
      for (int r = 0; r < 4; ++r) {
        const float v = acc[t][r] + sh.ep.red[tt][t][r][lane];
        const int e = t * 16 + (lane >> 4) * 4 + r;
        sh.ep.lgt[e][tt * 16 + l15] = v;
      }
  }
  __syncthreads();

  // routing: thread tid<64 handles token blockIdx*64 + tid (identical math
  // to the R13-verified k_route, logits sourced from LDS)
  if (tid < 64) {
    const int row = blockIdx.x * 64 + tid;

    float sb[E_N];
#pragma unroll
    for (int e = 0; e < E_N; ++e)
      sb[e] = 1.f / (1.f + expf(-sh.ep.lgt[e][tid])) + bias[e];

    float gs[8];
#pragma unroll
    for (int g = 0; g < 8; ++g) {
      float m1 = -__builtin_inff(), m2 = -__builtin_inff();
#pragma unroll
      for (int j = 0; j < 8; ++j) {
        float v = sb[g * 8 + j];
        if (v > m1) { m2 = m1; m1 = v; }
        else if (v > m2) { m2 = v; }
      }
      gs[g] = m1 + m2;
    }

    unsigned gmask = 0;
#pragma unroll
    for (int tsel = 0; tsel < 4; ++tsel) {
      float best = -__builtin_inff(); int bi = 0;
#pragma unroll
      for (int g = 0; g < 8; ++g) {
        bool avail = ((gmask >> g) & 1u) == 0u;
        if (avail && gs[g] > best) { best = gs[g]; bi = g; }
      }
      gmask |= (1u << bi);
    }

    unsigned long long tm = 0ull;
#pragma unroll
    for (int g = 0; g < 8; ++g)
      if (((gmask >> g) & 1u) == 0u) tm |= (0xFFull << (8 * g));

    float wv[8]; int io[8]; float wsum = 0.f;
#pragma unroll
    for (int tsel = 0; tsel < 8; ++tsel) {
      float best = -__builtin_inff(); int bi = 0;
#pragma unroll
      for (int e = 0; e < E_N; ++e) {
        bool avail = ((tm >> e) & 1ull) == 0ull;
        if (avail && sb[e] > best) { best = sb[e]; bi = e; }
      }
      tm |= (1ull << bi);
      float sv = best - bias[bi];
      wv[tsel] = sv; io[tsel] = bi; wsum += sv;
    }

    const float scale = 2.5f / wsum;
    float4 w0 = make_float4(wv[0] * scale, wv[1] * scale, wv[2] * scale, wv[3] * scale);
    float4 w1 = make_float4(wv[4] * scale, wv[5] * scale, wv[6] * scale, wv[7] * scale);
    float4 i0 = make_float4((float)io[0], (float)io[1], (float)io[2], (float)io[3]);
    float4 i1 = make_float4((float)io[4], (float)io[5], (float)io[6], (float)io[7]);
    *(float4*)(out_w + (size_t)row * 8)     = w0;
    *(float4*)(out_w + (size_t)row * 8 + 4) = w1;
    *(float4*)(out_i + (size_t)row * 8)     = i0;
    *(float4*)(out_i + (size_t)row * 8 + 4) = i1;
  }
}

extern "C" void kernel_launch(void* const* d_in, const int* in_sizes, int n_in,
                              void* d_out, int out_size, void* d_ws, size_t ws_size,
                              hipStream_t stream) {
  const float* x    = (const float*)d_in[0];
  const float* wgt  = (const float*)d_in[1];
  const float* bias = (const float*)d_in[2];
  float* out = (float*)d_out;
  unsigned short* wlp = (unsigned short*)d_ws;

  k_prep  <<<WL_USHORTS / 256, 256, 0, stream>>>(wgt, wlp);
  k_logits<<<T_TOK / 64,       512, 0, stream>>>(x, wlp, bias,
                                                 out, out + (size_t)T_TOK * 8);
}

// Round 16
// 73.690 us; speedup vs baseline: 12.0435x; 1.1234x over previous
//
#include <hip/hip_runtime.h>
#include <math.h>

#define T_TOK 32768
#define DIM   2048
#define E_N   64
#define KP    2048   // padded K (k==0 column is zero)

typedef float v4f    __attribute__((ext_vector_type(4)));
typedef float f32x4  __attribute__((ext_vector_type(4)));
typedef _Float16 f16x8 __attribute__((ext_vector_type(8)));
typedef __fp16 h2      __attribute__((ext_vector_type(2)));
typedef unsigned int u32x4 __attribute__((ext_vector_type(4)));

// fragment-linear W: wl[kc][s][t][lane][8]  (64 kc x 2 s x 4 t x 64 lanes x 8)
#define CHUNK_USH 4096                    // ushorts per kc chunk (8 KB)
#define WL_USHORTS (64 * CHUNK_USH)       // 512 KB total
#define RSCALE 4096.0f                    // residual pre-scale (2^12)
#define RINV   (1.0f / 4096.0f)

__device__ __forceinline__ unsigned short h2u(_Float16 h) {
  union { _Float16 h; unsigned short u; } c; c.h = h; return c.u;
}
__device__ __forceinline__ f16x8 ldh(const unsigned short* p) {
  union { u32x4 u; f16x8 h; } c; c.u = *(const u32x4*)p; return c.h;
}
__device__ __forceinline__ f16x8 packh(h2 a, h2 b, h2 c, h2 d) {
  union { h2 q[4]; f16x8 h; } t; t.q[0] = a; t.q[1] = b; t.q[2] = c; t.q[3] = d;
  return t.h;
}
__device__ __forceinline__ void async16(const void* g, void* l) {
  __builtin_amdgcn_global_load_lds((const __attribute__((address_space(1))) void*)g,
                                   (__attribute__((address_space(3))) void*)l,
                                   16, 0, 0);
}

// ---------------- kernel 0: W -> fragment-linear 2-way fp16 split ----------------
// wl[kc][s][t][lane][j]: expert e = t*16 + (lane&15), k = kc*32 + (lane>>4)*8 + j.
// s=0: fp16(w) (RNE); s=1: fp16((w - f32(s0)) * 2^12) (residual, pre-scaled normal).
__global__ __launch_bounds__(256) void k_prep(const float* __restrict__ w,
                                              unsigned short* __restrict__ wl) {
  int idx = blockIdx.x * 256 + threadIdx.x;    // 0 .. 262143
  int kc = idx >> 12;
  int r  = idx & 4095;
  int s  = r >> 11;
  int r2 = r & 2047;
  int t  = r2 >> 9;
  int r3 = r2 & 511;
  int lane = r3 >> 3;
  int j    = r3 & 7;
  int e = t * 16 + (lane & 15);
  int k = kc * 32 + (lane >> 4) * 8 + j;
  float f = (k == 0) ? 0.f : w[e * 2047 + (k - 1)];
  _Float16 h0 = (_Float16)f;                 // RNE
  float res = f - (float)h0;                 // exact
  _Float16 h1 = (_Float16)(res * RSCALE);    // RNE, normal-range
  wl[idx] = (s == 0) ? h2u(h0) : h2u(h1);
}

// ---------------- kernel 1: fused logits + routing ----------------
// Structure identical to the R14-verified kernel (8 waves = 4 tt x 2 kh,
// 512 blocks, LDS-staged double-buffered chunk pairs, 2-step x prefetch,
// counted vmcnt(2)). Arithmetic: 2-way fp16 split, 3 MFMA passes/chunk.
// acc0 = w0*x0; acc1 = w1'*x0 + w0*x1' (both residuals pre-scaled 2^12);
// final = acc0 + acc1*2^-12. Dropped w1*x1 term ~2^-22 relative.
__global__ __launch_bounds__(512, 4) void k_logits(const float* __restrict__ x,
                                                   const unsigned short* __restrict__ wl,
                                                   const float* __restrict__ bias,
                                                   float* __restrict__ out_w,
                                                   float* __restrict__ out_i) {
  __shared__ union ShMem {
    unsigned short wbuf[2][2][CHUNK_USH];   // [buf][kh][..] 32 KB
    struct { float red[4][4][4][64]; float lgt[E_N][65]; } ep;  // 32.6 KB
  } sh;
  const int tid  = threadIdx.x;
  const int lane = tid & 63;
  const int l15  = lane & 15;
  const int w8   = tid >> 6;           // 0..7
  const int tt   = w8 & 3;             // token-tile
  const int kh   = w8 >> 2;            // k-half
  const int tok0 = blockIdx.x * 64 + tt * 16;

  const float* xr = x + (size_t)(tok0 + l15) * DIM + kh * 1024 + (lane >> 4) * 8;

  // staging: half = tid>>8 stages chunk (c + half*32); lane-linear 16B dest
  const int half = tid >> 8;
  const int t256 = tid & 255;
  auto stage = [&](int c, int b) {
    const unsigned short* src = wl + (size_t)(c + half * 32) * CHUNK_USH;
#pragma unroll
    for (int i = 0; i < 2; ++i)
      async16(src + (i * 256 + t256) * 8, &sh.wbuf[b][half][(i * 256 + t256) * 8]);
  };

  f32x4 acc0[4], acc1[4];
#pragma unroll
  for (int t = 0; t < 4; ++t) { acc0[t] = (f32x4)(0.f); acc1[t] = (f32x4)(0.f); }

  // one step: split slot (s0,s1) -> reload slot for chunk xc -> LDS frags ->
  // 3-pass MFMA -> vmcnt(2) + barrier. rb = LDS read buf, sc/sb = stage args.
  auto step = [&](v4f& s0, v4f& s1, int rb, int sc, int sb, int xc) {
    if (sc < 32) stage(sc, sb);
    // 2-way fp16 split of the 8 x values (residuals exact, pre-scaled 2^12)
    h2 q0 = __builtin_amdgcn_cvt_pkrtz(s0.x, s0.y);
    h2 q1 = __builtin_amdgcn_cvt_pkrtz(s0.z, s0.w);
    h2 q2 = __builtin_amdgcn_cvt_pkrtz(s1.x, s1.y);
    h2 q3 = __builtin_amdgcn_cvt_pkrtz(s1.z, s1.w);
    float r0 = (s0.x - (float)q0.x) * RSCALE, r1 = (s0.y - (float)q0.y) * RSCALE;
    float r2 = (s0.z - (float)q1.x) * RSCALE, r3 = (s0.w - (float)q1.y) * RSCALE;
    float r4 = (s1.x - (float)q2.x) * RSCALE, r5 = (s1.y - (float)q2.y) * RSCALE;
    float r6 = (s1.z - (float)q3.x) * RSCALE, r7 = (s1.w - (float)q3.y) * RSCALE;
    h2 u0 = __builtin_amdgcn_cvt_pkrtz(r0, r1);
    h2 u1 = __builtin_amdgcn_cvt_pkrtz(r2, r3);
    h2 u2 = __builtin_amdgcn_cvt_pkrtz(r4, r5);
    h2 u3 = __builtin_amdgcn_cvt_pkrtz(r6, r7);
    f16x8 x0 = packh(q0, q1, q2, q3);
    f16x8 x1 = packh(u0, u1, u2, u3);
    // slot is dead now: reload it for chunk xc (2-step distance; dummy at tail)
    const float* nx = xr + ((xc < 32) ? xc * 32 : 0);
    s0 = *(const v4f*)(nx);
    s1 = *(const v4f*)(nx + 4);
    // 8 fragment reads from this wave's k-half (ds_read_b128, 1 KB each)
    f16x8 wf[2][4];
#pragma unroll
    for (int s = 0; s < 2; ++s)
#pragma unroll
      for (int t = 0; t < 4; ++t)
        wf[s][t] = ldh(&sh.wbuf[rb][kh][(s * 4 + t) * 512 + lane * 8]);
    // 3 passes: residual passes into acc1 (scaled 2^12), main into acc0
#pragma unroll
    for (int t = 0; t < 4; ++t)
      acc1[t] = __builtin_amdgcn_mfma_f32_16x16x32_f16(wf[1][t], x0, acc1[t], 0, 0, 0);
#pragma unroll
    for (int t = 0; t < 4; ++t)
      acc1[t] = __builtin_amdgcn_mfma_f32_16x16x32_f16(wf[0][t], x1, acc1[t], 0, 0, 0);
#pragma unroll
    for (int t = 0; t < 4; ++t)
      acc0[t] = __builtin_amdgcn_mfma_f32_16x16x32_f16(wf[0][t], x0, acc0[t], 0, 0, 0);
    // wait W-stage only (newest 2 outstanding = this step's x loads stay in flight)
    asm volatile("s_waitcnt vmcnt(2)" ::: "memory");
    __syncthreads();
  };

  // x slots: a = even chunks, b = odd chunks (2-step issue-to-use distance)
  v4f a0 = *(const v4f*)(xr);
  v4f a1 = *(const v4f*)(xr + 4);
  v4f b0 = *(const v4f*)(xr + 32);
  v4f b1 = *(const v4f*)(xr + 36);

  stage(0, 0);
  asm volatile("s_waitcnt vmcnt(0)" ::: "memory");
  __syncthreads();

  for (int cc = 0; cc < 32; cc += 2) {
    step(a0, a1, 0, cc + 1, 1, cc + 2);   // chunk cc   (reads buf0)
    step(b0, b1, 1, cc + 2, 0, cc + 3);   // chunk cc+1 (reads buf1)
  }

  // ---- epilogue: combine splits, kh-reduce, logits -> LDS, fused routing ----
  float comb[4][4];
#pragma unroll
  for (int t = 0; t < 4; ++t)
#pragma unroll
    for (int r = 0; r < 4; ++r)
      comb[t][r] = acc0[t][r] + acc1[t][r] * RINV;

  if (kh == 1) {
#pragma unroll
    for (int t = 0; t < 4; ++t)
#pragma unroll
      for (int r = 0; r < 4; ++r)
        sh.ep.red[tt][t][r][lane] = comb[t][r];   // lane-contiguous: conflict-free
  }
  __syncthreads();
  if (kh == 0) {
#pragma unroll
    for (int t = 0; t < 4; ++t)
#pragma unroll
      for (int r = 0; r < 4; ++r) {
        const float v = comb[t][r] + sh.ep.red[tt][t][r][lane];
        const int e = t * 16 + (lane >> 4) * 4 + r;
        sh.ep.lgt[e][tt * 16 + l15] = v;
      }
  }
  __syncthreads();

  // routing: thread tid<64 handles token blockIdx*64 + tid (R13/R14-verified)
  if (tid < 64) {
    const int row = blockIdx.x * 64 + tid;

    float sb[E_N];
#pragma unroll
    for (int e = 0; e < E_N; ++e)
      sb[e] = 1.f / (1.f + expf(-sh.ep.lgt[e][tid])) + bias[e];

    float gs[8];
#pragma unroll
    for (int g = 0; g < 8; ++g) {
      float m1 = -__builtin_inff(), m2 = -__builtin_inff();
#pragma unroll
      for (int j = 0; j < 8; ++j) {
        float v = sb[g * 8 + j];
        if (v > m1) { m2 = m1; m1 = v; }
        else if (v > m2) { m2 = v; }
      }
      gs[g] = m1 + m2;
    }

    unsigned gmask = 0;
#pragma unroll
    for (int tsel = 0; tsel < 4; ++tsel) {
      float best = -__builtin_inff(); int bi = 0;
#pragma unroll
      for (int g = 0; g < 8; ++g) {
        bool avail = ((gmask >> g) & 1u) == 0u;
        if (avail && gs[g] > best) { best = gs[g]; bi = g; }
      }
      gmask |= (1u << bi);
    }

    unsigned long long tm = 0ull;
#pragma unroll
    for (int g = 0; g < 8; ++g)
      if (((gmask >> g) & 1u) == 0u) tm |= (0xFFull << (8 * g));

    float wv[8]; int io[8]; float wsum = 0.f;
#pragma unroll
    for (int tsel = 0; tsel < 8; ++tsel) {
      float best = -__builtin_inff(); int bi = 0;
#pragma unroll
      for (int e = 0; e < E_N; ++e) {
        bool avail = ((tm >> e) & 1ull) == 0ull;
        if (avail && sb[e] > best) { best = sb[e]; bi = e; }
      }
      tm |= (1ull << bi);
      float sv = best - bias[bi];
      wv[tsel] = sv; io[tsel] = bi; wsum += sv;
    }

    const float scale = 2.5f / wsum;
    float4 w0 = make_float4(wv[0] * scale, wv[1] * scale, wv[2] * scale, wv[3] * scale);
    float4 w1 = make_float4(wv[4] * scale, wv[5] * scale, wv[6] * scale, wv[7] * scale);
    float4 i0 = make_float4((float)io[0], (float)io[1], (float)io[2], (float)io[3]);
    float4 i1 = make_float4((float)io[4], (float)io[5], (float)io[6], (float)io[7]);
    *(float4*)(out_w + (size_t)row * 8)     = w0;
    *(float4*)(out_w + (size_t)row * 8 + 4) = w1;
    *(float4*)(out_i + (size_t)row * 8)     = i0;
    *(float4*)(out_i + (size_t)row * 8 + 4) = i1;
  }
}

extern "C" void kernel_launch(void* const* d_in, const int* in_sizes, int n_in,
                              void* d_out, int out_size, void* d_ws, size_t ws_size,
                              hipStream_t stream) {
  const float* x    = (const float*)d_in[0];
  const float* wgt  = (const float*)d_in[1];
  const float* bias = (const float*)d_in[2];
  float* out = (float*)d_out;
  unsigned short* wlp = (unsigned short*)d_ws;

  k_prep  <<<WL_USHORTS / 256, 256, 0, stream>>>(wgt, wlp);
  k_logits<<<T_TOK / 64,       512, 0, stream>>>(x, wlp, bias,
                                                 out, out + (size_t)T_TOK * 8);
}

// Round 17
// 73.528 us; speedup vs baseline: 12.0700x; 1.0022x over previous
//
#include <hip/hip_runtime.h>
#include <math.h>

#define T_TOK 32768
#define DIM   2048
#define E_N   64
#define KP    2048   // padded K (k==0 column is zero)

typedef float v4f    __attribute__((ext_vector_type(4)));
typedef float f32x4  __attribute__((ext_vector_type(4)));
typedef _Float16 f16x8 __attribute__((ext_vector_type(8)));
typedef __fp16 h2      __attribute__((ext_vector_type(2)));
typedef unsigned int u32x4 __attribute__((ext_vector_type(4)));

// fragment-linear W: wl[kc][s][t][lane][8]  (64 kc x 2 s x 4 t x 64 lanes x 8)
#define CHUNK_USH 4096                    // ushorts per kc chunk (8 KB)
#define WL_USHORTS (64 * CHUNK_USH)       // 512 KB total
#define RSCALE 4096.0f                    // residual pre-scale (2^12)
#define RINV   (1.0f / 4096.0f)

__device__ __forceinline__ unsigned short h2u(_Float16 h) {
  union { _Float16 h; unsigned short u; } c; c.h = h; return c.u;
}
__device__ __forceinline__ f16x8 ldh(const unsigned short* p) {
  union { u32x4 u; f16x8 h; } c; c.u = *(const u32x4*)p; return c.h;
}
__device__ __forceinline__ f16x8 packh(h2 a, h2 b, h2 c, h2 d) {
  union { h2 q[4]; f16x8 h; } t; t.q[0] = a; t.q[1] = b; t.q[2] = c; t.q[3] = d;
  return t.h;
}
__device__ __forceinline__ void async16(const void* g, void* l) {
  __builtin_amdgcn_global_load_lds((const __attribute__((address_space(1))) void*)g,
                                   (__attribute__((address_space(3))) void*)l,
                                   16, 0, 0);
}

// ---------------- kernel 0: W -> fragment-linear 2-way fp16 split ----------------
// wl[kc][s][t][lane][j]: expert e = t*16 + (lane&15), k = kc*32 + (lane>>4)*8 + j.
// s=0: fp16(w) (RNE); s=1: fp16((w - f32(s0)) * 2^12) (residual, pre-scaled normal).
__global__ __launch_bounds__(256) void k_prep(const float* __restrict__ w,
                                              unsigned short* __restrict__ wl) {
  int idx = blockIdx.x * 256 + threadIdx.x;    // 0 .. 262143
  int kc = idx >> 12;
  int r  = idx & 4095;
  int s  = r >> 11;
  int r2 = r & 2047;
  int t  = r2 >> 9;
  int r3 = r2 & 511;
  int lane = r3 >> 3;
  int j    = r3 & 7;
  int e = t * 16 + (lane & 15);
  int k = kc * 32 + (lane >> 4) * 8 + j;
  float f = (k == 0) ? 0.f : w[e * 2047 + (k - 1)];
  _Float16 h0 = (_Float16)f;                 // RNE
  float res = f - (float)h0;                 // exact
  _Float16 h1 = (_Float16)(res * RSCALE);    // RNE, normal-range
  wl[idx] = (s == 0) ? h2u(h0) : h2u(h1);
}

// ---------------- kernel 1: fused logits + routing ----------------
// Wave = 32 tokens (TWO 16-token B-fragments share each W-fragment LDS read:
// per-token LDS traffic halved vs R16) x 64 experts x k-half. Block = 256 thr
// = 4 waves (tp x kh); grid 512 = 2 blocks/CU. LDS-staged double-buffered
// chunk pairs, 2-step x prefetch, counted vmcnt(4). fp16 2-way split math,
// fragment layouts, epilogue reduce + fused routing identical to R16-verified.
__global__ __launch_bounds__(256, 2) void k_logits(const float* __restrict__ x,
                                                   const unsigned short* __restrict__ wl,
                                                   const float* __restrict__ bias,
                                                   float* __restrict__ out_w,
                                                   float* __restrict__ out_i) {
  __shared__ union ShMem {
    unsigned short wbuf[2][2][CHUNK_USH];   // [buf][kh][..] 32 KB
    struct { float red[4][4][4][64]; float lgt[E_N][65]; } ep;  // 32.6 KB
  } sh;
  const int tid  = threadIdx.x;
  const int lane = tid & 63;
  const int l15  = lane & 15;
  const int w4   = tid >> 6;           // 0..3
  const int tp   = w4 & 1;             // token-pair tile (32 tokens)
  const int kh   = w4 >> 1;            // k-half
  const int tok0 = blockIdx.x * 64 + tp * 32;
  const int kq   = (lane >> 4) * 8;

  const float* xr0 = x + (size_t)(tok0 + l15) * DIM + kh * 1024 + kq;       // tg0
  const float* xr1 = xr0 + (size_t)16 * DIM;                                 // tg1

  // staging: half = tid>>7 stages chunk (c + half*32); lane-linear 16B dest
  const int half = tid >> 7;
  const int t128 = tid & 127;
  auto stage = [&](int c, int b) {
    const unsigned short* src = wl + (size_t)(c + half * 32) * CHUNK_USH;
#pragma unroll
    for (int i = 0; i < 4; ++i)
      async16(src + (i * 128 + t128) * 8, &sh.wbuf[b][half][(i * 128 + t128) * 8]);
  };

  f32x4 acc0[2][4], acc1[2][4];
#pragma unroll
  for (int g = 0; g < 2; ++g)
#pragma unroll
    for (int t = 0; t < 4; ++t) { acc0[g][t] = (f32x4)(0.f); acc1[g][t] = (f32x4)(0.f); }

  // split helper: 8 floats -> main f16x8 + residual f16x8 (pre-scaled 2^12)
  auto split = [&](v4f s0, v4f s1, f16x8& x0, f16x8& x1) {
    h2 q0 = __builtin_amdgcn_cvt_pkrtz(s0.x, s0.y);
    h2 q1 = __builtin_amdgcn_cvt_pkrtz(s0.z, s0.w);
    h2 q2 = __builtin_amdgcn_cvt_pkrtz(s1.x, s1.y);
    h2 q3 = __builtin_amdgcn_cvt_pkrtz(s1.z, s1.w);
    float r0 = (s0.x - (float)q0.x) * RSCALE, r1 = (s0.y - (float)q0.y) * RSCALE;
    float r2 = (s0.z - (float)q1.x) * RSCALE, r3 = (s0.w - (float)q1.y) * RSCALE;
    float r4 = (s1.x - (float)q2.x) * RSCALE, r5 = (s1.y - (float)q2.y) * RSCALE;
    float r6 = (s1.z - (float)q3.x) * RSCALE, r7 = (s1.w - (float)q3.y) * RSCALE;
    h2 u0 = __builtin_amdgcn_cvt_pkrtz(r0, r1);
    h2 u1 = __builtin_amdgcn_cvt_pkrtz(r2, r3);
    h2 u2 = __builtin_amdgcn_cvt_pkrtz(r4, r5);
    h2 u3 = __builtin_amdgcn_cvt_pkrtz(r6, r7);
    x0 = packh(q0, q1, q2, q3);
    x1 = packh(u0, u1, u2, u3);
  };

  // one step: split both token-groups -> reload slots for chunk xc -> 8 LDS
  // frag reads (shared by both groups) -> 24 MFMA -> vmcnt(4) + barrier.
  auto step = [&](v4f& s0, v4f& s1, v4f& s2, v4f& s3, int rb, int sc, int sb, int xc) {
    if (sc < 32) stage(sc, sb);
    f16x8 x0a, x1a, x0b, x1b;
    split(s0, s1, x0a, x1a);
    split(s2, s3, x0b, x1b);
    // slots dead: reload for chunk xc (2-step distance; dummy at tail)
    const float* n0 = xr0 + ((xc < 32) ? xc * 32 : 0);
    const float* n1 = xr1 + ((xc < 32) ? xc * 32 : 0);
    s0 = *(const v4f*)(n0);
    s1 = *(const v4f*)(n0 + 4);
    s2 = *(const v4f*)(n1);
    s3 = *(const v4f*)(n1 + 4);
    // 8 fragment reads from this wave's k-half (ds_read_b128, 1 KB each)
    f16x8 wf[2][4];
#pragma unroll
    for (int s = 0; s < 2; ++s)
#pragma unroll
      for (int t = 0; t < 4; ++t)
        wf[s][t] = ldh(&sh.wbuf[rb][kh][(s * 4 + t) * 512 + lane * 8]);
    // token-group 0: 3 passes (residuals into acc1, main into acc0)
#pragma unroll
    for (int t = 0; t < 4; ++t)
      acc1[0][t] = __builtin_amdgcn_mfma_f32_16x16x32_f16(wf[1][t], x0a, acc1[0][t], 0, 0, 0);
#pragma unroll
    for (int t = 0; t < 4; ++t)
      acc1[0][t] = __builtin_amdgcn_mfma_f32_16x16x32_f16(wf[0][t], x1a, acc1[0][t], 0, 0, 0);
#pragma unroll
    for (int t = 0; t < 4; ++t)
      acc0[0][t] = __builtin_amdgcn_mfma_f32_16x16x32_f16(wf[0][t], x0a, acc0[0][t], 0, 0, 0);
    // token-group 1
#pragma unroll
    for (int t = 0; t < 4; ++t)
      acc1[1][t] = __builtin_amdgcn_mfma_f32_16x16x32_f16(wf[1][t], x0b, acc1[1][t], 0, 0, 0);
#pragma unroll
    for (int t = 0; t < 4; ++t)
      acc1[1][t] = __builtin_amdgcn_mfma_f32_16x16x32_f16(wf[0][t], x1b, acc1[1][t], 0, 0, 0);
#pragma unroll
    for (int t = 0; t < 4; ++t)
      acc0[1][t] = __builtin_amdgcn_mfma_f32_16x16x32_f16(wf[0][t], x0b, acc0[1][t], 0, 0, 0);
    // wait W-stage only (newest 4 outstanding = this step's x loads stay in flight)
    asm volatile("s_waitcnt vmcnt(4)" ::: "memory");
    __syncthreads();
  };

  // x slots: a* = even chunks, b* = odd chunks (2-step issue-to-use distance)
  v4f a0 = *(const v4f*)(xr0);
  v4f a1 = *(const v4f*)(xr0 + 4);
  v4f a2 = *(const v4f*)(xr1);
  v4f a3 = *(const v4f*)(xr1 + 4);
  v4f b0 = *(const v4f*)(xr0 + 32);
  v4f b1 = *(const v4f*)(xr0 + 36);
  v4f b2 = *(const v4f*)(xr1 + 32);
  v4f b3 = *(const v4f*)(xr1 + 36);

  stage(0, 0);
  asm volatile("s_waitcnt vmcnt(0)" ::: "memory");
  __syncthreads();

  for (int cc = 0; cc < 32; cc += 2) {
    step(a0, a1, a2, a3, 0, cc + 1, 1, cc + 2);   // chunk cc   (reads buf0)
    step(b0, b1, b2, b3, 1, cc + 2, 0, cc + 3);   // chunk cc+1 (reads buf1)
  }

  // ---- epilogue: combine splits, kh-reduce, logits -> LDS, fused routing ----
  float comb[2][4][4];
#pragma unroll
  for (int g = 0; g < 2; ++g)
#pragma unroll
    for (int t = 0; t < 4; ++t)
#pragma unroll
      for (int r = 0; r < 4; ++r)
        comb[g][t][r] = acc0[g][t][r] + acc1[g][t][r] * RINV;

  if (kh == 1) {
#pragma unroll
    for (int g = 0; g < 2; ++g)
#pragma unroll
      for (int t = 0; t < 4; ++t)
#pragma unroll
        for (int r = 0; r < 4; ++r)
          sh.ep.red[tp * 2 + g][t][r][lane] = comb[g][t][r];   // conflict-free
  }
  __syncthreads();
  if (kh == 0) {
#pragma unroll
    for (int g = 0; g < 2; ++g)
#pragma unroll
      for (int t = 0; t < 4; ++t)
#pragma unroll
        for (int r = 0; r < 4; ++r) {
          const float v = comb[g][t][r] + sh.ep.red[tp * 2 + g][t][r][lane];
          const int e = t * 16 + (lane >> 4) * 4 + r;
          sh.ep.lgt[e][(tp * 2 + g) * 16 + l15] = v;
        }
  }
  __syncthreads();

  // routing: thread tid<64 handles token blockIdx*64 + tid (R13-R16-verified)
  if (tid < 64) {
    const int row = blockIdx.x * 64 + tid;

    float sb[E_N];
#pragma unroll
    for (int e = 0; e < E_N; ++e)
      sb[e] = 1.f / (1.f + expf(-sh.ep.lgt[e][tid])) + bias[e];

    float gs[8];
#pragma unroll
    for (int g = 0; g < 8; ++g) {
      float m1 = -__builtin_inff(), m2 = -__builtin_inff();
#pragma unroll
      for (int j = 0; j < 8; ++j) {
        float v = sb[g * 8 + j];
        if (v > m1) { m2 = m1; m1 = v; }
        else if (v > m2) { m2 = v; }
      }
      gs[g] = m1 + m2;
    }

    unsigned gmask = 0;
#pragma unroll
    for (int tsel = 0; tsel < 4; ++tsel) {
      float best = -__builtin_inff(); int bi = 0;
#pragma unroll
      for (int g = 0; g < 8; ++g) {
        bool avail = ((gmask >> g) & 1u) == 0u;
        if (avail && gs[g] > best) { best = gs[g]; bi = g; }
      }
      gmask |= (1u << bi);
    }

    unsigned long long tm = 0ull;
#pragma unroll
    for (int g = 0; g < 8; ++g)
      if (((gmask >> g) & 1u) == 0u) tm |= (0xFFull << (8 * g));

    float wv[8]; int io[8]; float wsum = 0.f;
#pragma unroll
    for (int tsel = 0; tsel < 8; ++tsel) {
      float best = -__builtin_inff(); int bi = 0;
#pragma unroll
      for (int e = 0; e < E_N; ++e) {
        bool avail = ((tm >> e) & 1ull) == 0ull;
        if (avail && sb[e] > best) { best = sb[e]; bi = e; }
      }
      tm |= (1ull << bi);
      float sv = best - bias[bi];
      wv[tsel] = sv; io[tsel] = bi; wsum += sv;
    }

    const float scale = 2.5f / wsum;
    float4 w0 = make_float4(wv[0] * scale, wv[1] * scale, wv[2] * scale, wv[3] * scale);
    float4 w1 = make_float4(wv[4] * scale, wv[5] * scale, wv[6] * scale, wv[7] * scale);
    float4 i0 = make_float4((float)io[0], (float)io[1], (float)io[2], (float)io[3]);
    float4 i1 = make_float4((float)io[4], (float)io[5], (float)io[6], (float)io[7]);
    *(float4*)(out_w + (size_t)row * 8)     = w0;
    *(float4*)(out_w + (size_t)row * 8 + 4) = w1;
    *(float4*)(out_i + (size_t)row * 8)     = i0;
    *(float4*)(out_i + (size_t)row * 8 + 4) = i1;
  }
}

extern "C" void kernel_launch(void* const* d_in, const int* in_sizes, int n_in,
                              void* d_out, int out_size, void* d_ws, size_t ws_size,
                              hipStream_t stream) {
  const float* x    = (const float*)d_in[0];
  const float* wgt  = (const float*)d_in[1];
  const float* bias = (const float*)d_in[2];
  float* out = (float*)d_out;
  unsigned short* wlp = (unsigned short*)d_ws;

  k_prep  <<<WL_USHORTS / 256, 256, 0, stream>>>(wgt, wlp);
  k_logits<<<T_TOK / 64,       256, 0, stream>>>(x, wlp, bias,
                                                 out, out + (size_t)T_TOK * 8);
}

// Round 18
// 71.019 us; speedup vs baseline: 12.4966x; 1.0353x over previous
//
#include <hip/hip_runtime.h>
#include <math.h>

#define T_TOK 32768
#define DIM   2048
#define E_N   64
#define KP    2048   // padded K (k==0 column is zero)

typedef float v4f    __attribute__((ext_vector_type(4)));
typedef float f32x4  __attribute__((ext_vector_type(4)));
typedef _Float16 f16x8 __attribute__((ext_vector_type(8)));
typedef __fp16 h2      __attribute__((ext_vector_type(2)));
typedef unsigned int u32x4 __attribute__((ext_vector_type(4)));

// fragment-linear W: wl[kc][s][t][lane][8]  (64 kc x 2 s x 4 t x 64 lanes x 8)
#define CHUNK_USH 4096                    // ushorts per kc chunk (8 KB)
#define WL_USHORTS (64 * CHUNK_USH)       // 512 KB total
#define RSCALE 4096.0f                    // residual pre-scale (2^12)
#define RINV   (1.0f / 4096.0f)

__device__ __forceinline__ unsigned short h2u(_Float16 h) {
  union { _Float16 h; unsigned short u; } c; c.h = h; return c.u;
}
__device__ __forceinline__ f16x8 ldh(const unsigned short* p) {
  union { u32x4 u; f16x8 h; } c; c.u = *(const u32x4*)p; return c.h;
}
__device__ __forceinline__ f16x8 packh(h2 a, h2 b, h2 c, h2 d) {
  union { h2 q[4]; f16x8 h; } t; t.q[0] = a; t.q[1] = b; t.q[2] = c; t.q[3] = d;
  return t.h;
}
__device__ __forceinline__ void async16(const void* g, void* l) {
  __builtin_amdgcn_global_load_lds((const __attribute__((address_space(1))) void*)g,
                                   (__attribute__((address_space(3))) void*)l,
                                   16, 0, 0);
}

// ---------------- kernel 0: W -> fragment-linear 2-way fp16 split ----------------
// wl[kc][s][t][lane][j]: expert e = t*16 + (lane&15), k = kc*32 + (lane>>4)*8 + j.
// s=0: fp16(w) (RNE); s=1: fp16((w - f32(s0)) * 2^12) (residual, pre-scaled normal).
__global__ __launch_bounds__(256) void k_prep(const float* __restrict__ w,
                                              unsigned short* __restrict__ wl) {
  int idx = blockIdx.x * 256 + threadIdx.x;    // 0 .. 262143
  int kc = idx >> 12;
  int r  = idx & 4095;
  int s  = r >> 11;
  int r2 = r & 2047;
  int t  = r2 >> 9;
  int r3 = r2 & 511;
  int lane = r3 >> 3;
  int j    = r3 & 7;
  int e = t * 16 + (lane & 15);
  int k = kc * 32 + (lane >> 4) * 8 + j;
  float f = (k == 0) ? 0.f : w[e * 2047 + (k - 1)];
  _Float16 h0 = (_Float16)f;                 // RNE
  float res = f - (float)h0;                 // exact
  _Float16 h1 = (_Float16)(res * RSCALE);    // RNE, normal-range
  wl[idx] = (s == 0) ? h2u(h0) : h2u(h1);
}

// ---------------- kernel 1: fused logits + routing ----------------
// R17 structure (wave = 32 tokens x 64 experts x k-half; 4 waves/block;
// 512 blocks; LDS-staged double-buffered chunk pairs; 2-step x prefetch)
// with ONE change: the in-loop __syncthreads (which forces a compiler
// vmcnt(0) full drain, serializing the x prefetch every step) is replaced
// by counted vmcnt(4) + RAW s_barrier, so x loads genuinely stay in
// flight across steps (T3/T4). Compiler-level "" memory fences prevent
// hoisting LDS reads across the raw barrier.
__global__ __launch_bounds__(256, 2) void k_logits(const float* __restrict__ x,
                                                   const unsigned short* __restrict__ wl,
                                                   const float* __restrict__ bias,
                                                   float* __restrict__ out_w,
                                                   float* __restrict__ out_i) {
  __shared__ union ShMem {
    unsigned short wbuf[2][2][CHUNK_USH];   // [buf][kh][..] 32 KB
    struct { float red[4][4][4][64]; float lgt[E_N][65]; } ep;  // 32.6 KB
  } sh;
  const int tid  = threadIdx.x;
  const int lane = tid & 63;
  const int l15  = lane & 15;
  const int w4   = tid >> 6;           // 0..3
  const int tp   = w4 & 1;             // token-pair tile (32 tokens)
  const int kh   = w4 >> 1;            // k-half
  const int tok0 = blockIdx.x * 64 + tp * 32;
  const int kq   = (lane >> 4) * 8;

  const float* xr0 = x + (size_t)(tok0 + l15) * DIM + kh * 1024 + kq;       // tg0
  const float* xr1 = xr0 + (size_t)16 * DIM;                                 // tg1

  // staging: half = tid>>7 stages chunk (c + half*32); lane-linear 16B dest
  const int half = tid >> 7;
  const int t128 = tid & 127;
  auto stage = [&](int c, int b) {
    const unsigned short* src = wl + (size_t)(c + half * 32) * CHUNK_USH;
#pragma unroll
    for (int i = 0; i < 4; ++i)
      async16(src + (i * 128 + t128) * 8, &sh.wbuf[b][half][(i * 128 + t128) * 8]);
  };

  f32x4 acc0[2][4], acc1[2][4];
#pragma unroll
  for (int g = 0; g < 2; ++g)
#pragma unroll
    for (int t = 0; t < 4; ++t) { acc0[g][t] = (f32x4)(0.f); acc1[g][t] = (f32x4)(0.f); }

  // split helper: 8 floats -> main f16x8 + residual f16x8 (pre-scaled 2^12)
  auto split = [&](v4f s0, v4f s1, f16x8& x0, f16x8& x1) {
    h2 q0 = __builtin_amdgcn_cvt_pkrtz(s0.x, s0.y);
    h2 q1 = __builtin_amdgcn_cvt_pkrtz(s0.z, s0.w);
    h2 q2 = __builtin_amdgcn_cvt_pkrtz(s1.x, s1.y);
    h2 q3 = __builtin_amdgcn_cvt_pkrtz(s1.z, s1.w);
    float r0 = (s0.x - (float)q0.x) * RSCALE, r1 = (s0.y - (float)q0.y) * RSCALE;
    float r2 = (s0.z - (float)q1.x) * RSCALE, r3 = (s0.w - (float)q1.y) * RSCALE;
    float r4 = (s1.x - (float)q2.x) * RSCALE, r5 = (s1.y - (float)q2.y) * RSCALE;
    float r6 = (s1.z - (float)q3.x) * RSCALE, r7 = (s1.w - (float)q3.y) * RSCALE;
    h2 u0 = __builtin_amdgcn_cvt_pkrtz(r0, r1);
    h2 u1 = __builtin_amdgcn_cvt_pkrtz(r2, r3);
    h2 u2 = __builtin_amdgcn_cvt_pkrtz(r4, r5);
    h2 u3 = __builtin_amdgcn_cvt_pkrtz(r6, r7);
    x0 = packh(q0, q1, q2, q3);
    x1 = packh(u0, u1, u2, u3);
  };

  // one step: split both token-groups -> reload slots for chunk xc -> 8 LDS
  // frag reads (shared by both groups) -> 24 MFMA -> vmcnt(4) + RAW barrier.
  auto step = [&](v4f& s0, v4f& s1, v4f& s2, v4f& s3, int rb, int sc, int sb, int xc) {
    if (sc < 32) stage(sc, sb);
    f16x8 x0a, x1a, x0b, x1b;
    split(s0, s1, x0a, x1a);
    split(s2, s3, x0b, x1b);
    // slots dead: reload for chunk xc (2-step distance; dummy at tail)
    const float* n0 = xr0 + ((xc < 32) ? xc * 32 : 0);
    const float* n1 = xr1 + ((xc < 32) ? xc * 32 : 0);
    s0 = *(const v4f*)(n0);
    s1 = *(const v4f*)(n0 + 4);
    s2 = *(const v4f*)(n1);
    s3 = *(const v4f*)(n1 + 4);
    // 8 fragment reads from this wave's k-half (ds_read_b128, 1 KB each)
    f16x8 wf[2][4];
#pragma unroll
    for (int s = 0; s < 2; ++s)
#pragma unroll
      for (int t = 0; t < 4; ++t)
        wf[s][t] = ldh(&sh.wbuf[rb][kh][(s * 4 + t) * 512 + lane * 8]);
    // token-group 0: 3 passes (residuals into acc1, main into acc0)
#pragma unroll
    for (int t = 0; t < 4; ++t)
      acc1[0][t] = __builtin_amdgcn_mfma_f32_16x16x32_f16(wf[1][t], x0a, acc1[0][t], 0, 0, 0);
#pragma unroll
    for (int t = 0; t < 4; ++t)
      acc1[0][t] = __builtin_amdgcn_mfma_f32_16x16x32_f16(wf[0][t], x1a, acc1[0][t], 0, 0, 0);
#pragma unroll
    for (int t = 0; t < 4; ++t)
      acc0[0][t] = __builtin_amdgcn_mfma_f32_16x16x32_f16(wf[0][t], x0a, acc0[0][t], 0, 0, 0);
    // token-group 1
#pragma unroll
    for (int t = 0; t < 4; ++t)
      acc1[1][t] = __builtin_amdgcn_mfma_f32_16x16x32_f16(wf[1][t], x0b, acc1[1][t], 0, 0, 0);
#pragma unroll
    for (int t = 0; t < 4; ++t)
      acc1[1][t] = __builtin_amdgcn_mfma_f32_16x16x32_f16(wf[0][t], x1b, acc1[1][t], 0, 0, 0);
#pragma unroll
    for (int t = 0; t < 4; ++t)
      acc0[1][t] = __builtin_amdgcn_mfma_f32_16x16x32_f16(wf[0][t], x0b, acc0[1][t], 0, 0, 0);
    // counted wait: drains this step's 4 stage loads (oldest) + any older x
    // loads; leaves this step's 4 x loads in flight ACROSS the raw barrier.
    asm volatile("s_waitcnt vmcnt(4)" ::: "memory");
    __builtin_amdgcn_s_barrier();
    asm volatile("" ::: "memory");
  };

  // x slots: a* = even chunks, b* = odd chunks (2-step issue-to-use distance)
  v4f a0 = *(const v4f*)(xr0);
  v4f a1 = *(const v4f*)(xr0 + 4);
  v4f a2 = *(const v4f*)(xr1);
  v4f a3 = *(const v4f*)(xr1 + 4);
  v4f b0 = *(const v4f*)(xr0 + 32);
  v4f b1 = *(const v4f*)(xr0 + 36);
  v4f b2 = *(const v4f*)(xr1 + 32);
  v4f b3 = *(const v4f*)(xr1 + 36);

  stage(0, 0);
  asm volatile("s_waitcnt vmcnt(0)" ::: "memory");
  __syncthreads();

  for (int cc = 0; cc < 32; cc += 2) {
    step(a0, a1, a2, a3, 0, cc + 1, 1, cc + 2);   // chunk cc   (reads buf0)
    step(b0, b1, b2, b3, 1, cc + 2, 0, cc + 3);   // chunk cc+1 (reads buf1)
  }

  // ---- epilogue: combine splits, kh-reduce, logits -> LDS, fused routing ----
  float comb[2][4][4];
#pragma unroll
  for (int g = 0; g < 2; ++g)
#pragma unroll
    for (int t = 0; t < 4; ++t)
#pragma unroll
      for (int r = 0; r < 4; ++r)
        comb[g][t][r] = acc0[g][t][r] + acc1[g][t][r] * RINV;

  if (kh == 1) {
#pragma unroll
    for (int g = 0; g < 2; ++g)
#pragma unroll
      for (int t = 0; t < 4; ++t)
#pragma unroll
        for (int r = 0; r < 4; ++r)
          sh.ep.red[tp * 2 + g][t][r][lane] = comb[g][t][r];   // conflict-free
  }
  __syncthreads();
  if (kh == 0) {
#pragma unroll
    for (int g = 0; g < 2; ++g)
#pragma unroll
      for (int t = 0; t < 4; ++t)
#pragma unroll
        for (int r = 0; r < 4; ++r) {
          const float v = comb[g][t][r] + sh.ep.red[tp * 2 + g][t][r][lane];
          const int e = t * 16 + (lane >> 4) * 4 + r;
          sh.ep.lgt[e][(tp * 2 + g) * 16 + l15] = v;
        }
  }
  __syncthreads();

  // routing: thread tid<64 handles token blockIdx*64 + tid (R13-R17-verified)
  if (tid < 64) {
    const int row = blockIdx.x * 64 + tid;

    float sb[E_N];
#pragma unroll
    for (int e = 0; e < E_N; ++e)
      sb[e] = 1.f / (1.f + expf(-sh.ep.lgt[e][tid])) + bias[e];

    float gs[8];
#pragma unroll
    for (int g = 0; g < 8; ++g) {
      float m1 = -__builtin_inff(), m2 = -__builtin_inff();
#pragma unroll
      for (int j = 0; j < 8; ++j) {
        float v = sb[g * 8 + j];
        if (v > m1) { m2 = m1; m1 = v; }
        else if (v > m2) { m2 = v; }
      }
      gs[g] = m1 + m2;
    }

    unsigned gmask = 0;
#pragma unroll
    for (int tsel = 0; tsel < 4; ++tsel) {
      float best = -__builtin_inff(); int bi = 0;
#pragma unroll
      for (int g = 0; g < 8; ++g) {
        bool avail = ((gmask >> g) & 1u) == 0u;
        if (avail && gs[g] > best) { best = gs[g]; bi = g; }
      }
      gmask |= (1u << bi);
    }

    unsigned long long tm = 0ull;
#pragma unroll
    for (int g = 0; g < 8; ++g)
      if (((gmask >> g) & 1u) == 0u) tm |= (0xFFull << (8 * g));

    float wv[8]; int io[8]; float wsum = 0.f;
#pragma unroll
    for (int tsel = 0; tsel < 8; ++tsel) {
      float best = -__builtin_inff(); int bi = 0;
#pragma unroll
      for (int e = 0; e < E_N; ++e) {
        bool avail = ((tm >> e) & 1ull) == 0ull;
        if (avail && sb[e] > best) { best = sb[e]; bi = e; }
      }
      tm |= (1ull << bi);
      float sv = best - bias[bi];
      wv[tsel] = sv; io[tsel] = bi; wsum += sv;
    }

    const float scale = 2.5f / wsum;
    float4 w0 = make_float4(wv[0] * scale, wv[1] * scale, wv[2] * scale, wv[3] * scale);
    float4 w1 = make_float4(wv[4] * scale, wv[5] * scale, wv[6] * scale, wv[7] * scale);
    float4 i0 = make_float4((float)io[0], (float)io[1], (float)io[2], (float)io[3]);
    float4 i1 = make_float4((float)io[4], (float)io[5], (float)io[6], (float)io[7]);
    *(float4*)(out_w + (size_t)row * 8)     = w0;
    *(float4*)(out_w + (size_t)row * 8 + 4) = w1;
    *(float4*)(out_i + (size_t)row * 8)     = i0;
    *(float4*)(out_i + (size_t)row * 8 + 4) = i1;
  }
}

extern "C" void kernel_launch(void* const* d_in, const int* in_sizes, int n_in,
                              void* d_out, int out_size, void* d_ws, size_t ws_size,
                              hipStream_t stream) {
  const float* x    = (const float*)d_in[0];
  const float* wgt  = (const float*)d_in[1];
  const float* bias = (const float*)d_in[2];
  float* out = (float*)d_out;
  unsigned short* wlp = (unsigned short*)d_ws;

  k_prep  <<<WL_USHORTS / 256, 256, 0, stream>>>(wgt, wlp);
  k_logits<<<T_TOK / 64,       256, 0, stream>>>(x, wlp, bias,
                                                 out, out + (size_t)T_TOK * 8);
}